// Round 8
// baseline (217.120 us; speedup 1.0000x reference)
//
#include <hip/hip_runtime.h>
#include <cmath>

typedef unsigned short u16;
typedef __bf16 bf16x8 __attribute__((ext_vector_type(8)));
typedef float f32x4 __attribute__((ext_vector_type(4)));

__device__ __forceinline__ u16 f2bf(float f) {
  unsigned u = __float_as_uint(f);
  u += 0x7fffu + ((u >> 16) & 1u);
  return (u16)(u >> 16);
}
__device__ __forceinline__ float bf2f(u16 h) {
  return __uint_as_float(((unsigned)h) << 16);
}
__device__ __forceinline__ f32x4 mfma_bf16(bf16x8 a, bf16x8 b, f32x4 c) {
  return __builtin_amdgcn_mfma_f32_16x16x32_bf16(a, b, c, 0, 0, 0);
}
__device__ __forceinline__ float gelu_exact(float x) {
  return 0.5f * x * (1.0f + erff(x * 0.70710678118654752440f));
}

__device__ __forceinline__ void gload16(const void* g, void* l) {
  __builtin_amdgcn_global_load_lds(
      (const __attribute__((address_space(1))) unsigned*)g,
      (__attribute__((address_space(3))) unsigned*)l, 16, 0, 0);
}

// B=16, C=128, H=64, W=64. Padded NHWC: [B][66][66][128], data at y+1,x+1.
__device__ __forceinline__ size_t pidx(int b, int y, int x) {
  return ((size_t)(b * 66 + y) * 66 + x) * 128;
}

__device__ __forceinline__ void border_yx(int k, int& y, int& x) {
  if (k < 66) { y = 0; x = k; }
  else if (k < 132) { y = 65; x = k - 66; }
  else if (k < 196) { y = k - 131; x = 0; }
  else { y = k - 195; x = 65; }
}

// ---------------- pack: X -> padded NHWC bf16, weights -> B-frag, X borders=0
__global__ __launch_bounds__(256) void pack_xw(
    const float* __restrict__ Fin, u16* __restrict__ Xp,
    const float* __restrict__ w0, const float* __restrict__ w1,
    const float* __restrict__ w2, const float* __restrict__ w3,
    const float* __restrict__ w4, u16* __restrict__ Wpk) {
  const int tid = threadIdx.x;
  const int bid = blockIdx.x;
  if (bid < 1024) {
    __shared__ float T[64 * 129];
    const int b = bid >> 6, y = bid & 63;
#pragma unroll
    for (int i = 0; i < 32; ++i) {
      int idx = tid + i * 256;
      int c = idx >> 6, x = idx & 63;
      T[x * 129 + c] = Fin[(size_t)(b * 128 + c) * 4096 + y * 64 + x];
    }
    __syncthreads();
#pragma unroll
    for (int i = 0; i < 4; ++i) {
      int chunk = tid + i * 256;
      int x = chunk >> 4;
      int c0 = (chunk & 15) * 8;
      u16 tmp[8];
#pragma unroll
      for (int e = 0; e < 8; ++e) tmp[e] = f2bf(T[x * 129 + c0 + e]);
      *reinterpret_cast<uint4*>(Xp + pidx(b, y + 1, x + 1) + c0) =
          *reinterpret_cast<const uint4*>(tmp);
    }
  } else if (bid < 1384) {
    int gid = (bid - 1024) * 256 + tid;  // 92160 total
    int lane = gid & 63;
    int nblk = (gid >> 6) & 7;
    int step = (gid >> 9) % 36;
    int conv = gid / (512 * 36);
    if (conv >= 5) return;
    const float* w = conv == 0 ? w0 : conv == 1 ? w1 : conv == 2 ? w2 : conv == 3 ? w3 : w4;
    int tap = step >> 2, cc = step & 3;
    int dy = tap / 3, dx = tap % 3;
    int co = nblk * 16 + (lane & 15);
    int ci0 = cc * 32 + (lane >> 4) * 8;
    u16 tmp[8];
#pragma unroll
    for (int e = 0; e < 8; ++e)
      tmp[e] = f2bf(w[((size_t)(co * 128 + ci0 + e) * 3 + dy) * 3 + dx]);
    size_t off = ((size_t)conv * 36 * 8 * 64 + (size_t)((step * 8 + nblk) * 64 + lane)) * 8;
    *reinterpret_cast<uint4*>(Wpk + off) = *reinterpret_cast<const uint4*>(tmp);
  } else {
    // zero Xp borders: 4160 positions of 256B
    int p = (bid - 1384) * 16 + (tid >> 4);
    int b = p / 260, k = p % 260;
    int y, x;
    border_yx(k, y, x);
    *reinterpret_cast<uint4*>(Xp + pidx(b, y, x) + (tid & 15) * 8) =
        make_uint4(0u, 0u, 0u, 0u);
  }
}

// ======== stage full-C A tile (4 padded rows x 66 x 128ch = 67584B) ========
// linear LDS dest, pre-swizzled global source (swizzle = chunk ^ (xs&7))
__device__ __forceinline__ void stageA_full(const u16* __restrict__ Xp, char* Xs,
                                            int tid, int b, int y0p) {
#pragma unroll
  for (int i = 0; i < 17; ++i) {
    if (i == 16 && tid >= 128) break;
    int j = i * 256 + tid;          // chunk 0..4223
    int row = j >> 4, c16 = j & 15; // row = ys*66+xs
    int ys = row / 66, xs = row - ys * 66;
    const u16* src = Xp + pidx(b, y0p + ys, xs) + ((c16 ^ (xs & 7)) << 3);
    gload16(src, Xs + j * 16);
  }
}

// ---------------- conv3x3 implicit GEMM, fused-QKV / f1 / f2 ----------------
// MODE 0: QKV fused (acc[3]): Q,K fragment-packed; V natural
// MODE 1: f1 (gelu -> padded Hp)
// MODE 2: f2 (f32 NCHW out + residual)
template <int MODE>
__global__ __launch_bounds__(256, 2) void convX(
    const u16* __restrict__ Xin, const u16* __restrict__ Wp,
    const float* __restrict__ b0, const float* __restrict__ b1,
    const float* __restrict__ b2, u16* __restrict__ O0, u16* __restrict__ O1,
    u16* __restrict__ O2, float* __restrict__ OutF,
    const u16* __restrict__ Resid) {
  constexpr int NCV = (MODE == 0) ? 3 : 1;
  __shared__ alignas(16) char smem[67584];
  const int tid = threadIdx.x;
  const int lane = tid & 63, wv = tid >> 6;
  const int wm = wv >> 1, wn = wv & 1;
  int mt = blockIdx.x;
  mt = (mt & 7) * 64 + (mt >> 3);  // 512 blocks, bijective XCD swizzle
  const int b = mt >> 5, yp = mt & 31;
  const int lm = lane & 15, lq = lane >> 4;

  stageA_full(Xin, smem, tid, b, yp * 2);
  __syncthreads();

  f32x4 acc[NCV][4][4];
#pragma unroll
  for (int c = 0; c < NCV; ++c)
#pragma unroll
    for (int i = 0; i < 4; ++i)
#pragma unroll
      for (int j = 0; j < 4; ++j) acc[c][i][j] = f32x4{0.f, 0.f, 0.f, 0.f};

  const u16* wlane = Wp + (size_t)lane * 8;

#pragma unroll 1
  for (int tap = 0; tap < 9; ++tap) {
    const int dy = (tap * 11) >> 5;  // tap/3
    const int dx = tap - dy * 3;
#pragma unroll
    for (int cc = 0; cc < 4; ++cc) {
      const int step = tap * 4 + cc;
      bf16x8 af[4];
#pragma unroll
      for (int i = 0; i < 4; ++i) {
        int xs = i * 16 + lm + dx;
        unsigned off = (unsigned)((((wm + dy) * 66 + xs) * 128 + cc * 32 + lq * 8) * 2) ^
                       (unsigned)((xs & 7) << 4);
        af[i] = *reinterpret_cast<const bf16x8*>(smem + off);
      }
#pragma unroll
      for (int cv = 0; cv < NCV; ++cv) {
        bf16x8 bfr[4];
#pragma unroll
        for (int j = 0; j < 4; ++j)
          bfr[j] = *reinterpret_cast<const bf16x8*>(
              wlane + (size_t)cv * 147456 + (size_t)((step * 8 + wn * 4 + j) * 64) * 8);
        __builtin_amdgcn_s_setprio(1);
#pragma unroll
        for (int i = 0; i < 4; ++i)
#pragma unroll
          for (int j = 0; j < 4; ++j)
            acc[cv][i][j] = mfma_bf16(af[i], bfr[j], acc[cv][i][j]);
        __builtin_amdgcn_s_setprio(0);
      }
    }
  }

  __syncthreads();  // LDS dead; reuse for epilogues

  if (MODE == 0) {
    u16* T = (u16*)smem;  // [128][136]
#pragma unroll 1
    for (int cv = 0; cv < 2; ++cv) {
      const float* bias = cv == 0 ? b0 : b1;
      u16* OutB = cv == 0 ? O0 : O1;
#pragma unroll
      for (int i = 0; i < 4; ++i)
#pragma unroll
        for (int j = 0; j < 4; ++j) {
          int n = wn * 64 + j * 16 + lm;
          float bs = bias[n];
#pragma unroll
          for (int r = 0; r < 4; ++r) {
            int m = wm * 64 + i * 16 + lq * 4 + r;
            T[n * 136 + m] = f2bf(acc[cv][i][j][r] + bs);
          }
        }
      __syncthreads();
#pragma unroll
      for (int it = 0; it < 8; ++it) {
        int item = tid + it * 256;
        int l = item & 63, cb = (item >> 6) & 7, ksl = item >> 9;
        int c = cb * 16 + (l & 15);
        int mloc = ksl * 32 + (l >> 4) * 8;
        int ks = yp * 4 + ksl;
        *reinterpret_cast<uint4*>(
            OutB + (size_t)(((b * 128 + ks) * 8 + cb) * 64 + l) * 8) =
            *reinterpret_cast<const uint4*>(T + c * 136 + mloc);
      }
      __syncthreads();
    }
    // V natural [pos][ch]
#pragma unroll
    for (int i = 0; i < 4; ++i)
#pragma unroll
      for (int j = 0; j < 4; ++j) {
        int n = wn * 64 + j * 16 + lm;
        float bs = b2[n];
#pragma unroll
        for (int r = 0; r < 4; ++r) {
          int m = wm * 64 + i * 16 + lq * 4 + r;
          T[m * 136 + n] = f2bf(acc[2][i][j][r] + bs);
        }
      }
    __syncthreads();
    int rr = tid >> 1, hf = tid & 1;
    const uint4* src = reinterpret_cast<const uint4*>(T + rr * 136 + hf * 64);
    uint4* dst = reinterpret_cast<uint4*>(O2 + ((size_t)(mt * 128 + rr) * 128 + hf * 64));
#pragma unroll
    for (int k = 0; k < 8; ++k) dst[k] = src[k];
  } else if (MODE == 1) {
    u16* T = (u16*)smem;  // [128][136]
#pragma unroll
    for (int i = 0; i < 4; ++i)
#pragma unroll
      for (int j = 0; j < 4; ++j) {
        int n = wn * 64 + j * 16 + lm;
        float bs = b0[n];
#pragma unroll
        for (int r = 0; r < 4; ++r) {
          int m = wm * 64 + i * 16 + lq * 4 + r;
          T[m * 136 + n] = f2bf(gelu_exact(acc[0][i][j][r] + bs));
        }
      }
    __syncthreads();
    int rr = tid >> 1, hf = tid & 1;
    int y = yp * 2 + (rr >> 6), x = rr & 63;
    const uint4* src = reinterpret_cast<const uint4*>(T + rr * 136 + hf * 64);
    uint4* dst = reinterpret_cast<uint4*>(O0 + pidx(b, y + 1, x + 1) + hf * 64);
#pragma unroll
    for (int k = 0; k < 8; ++k) dst[k] = src[k];
  } else {
    // f2: single-pass f32 transpose [128][132] = 67584B exactly
    float* Tf = (float*)smem;
#pragma unroll
    for (int i = 0; i < 4; ++i)
#pragma unroll
      for (int j = 0; j < 4; ++j) {
        int n = wn * 64 + j * 16 + lm;
        float bs = b0[n];
        int m0 = wm * 64 + i * 16 + lq * 4;
        int y = yp * 2 + (m0 >> 6), x = m0 & 63;
        const u16* rp = Resid + pidx(b, y + 1, x + 1) + n;
#pragma unroll
        for (int r = 0; r < 4; ++r)
          Tf[n * 132 + m0 + r] = acc[0][i][j][r] + bs + bf2f(rp[r * 128]);
      }
    __syncthreads();
    int n2 = tid >> 1, seg = tid & 1;
    float* dst = OutF + ((size_t)(b * 128 + n2) * 4096 + yp * 128 + seg * 64);
    const float* src = Tf + n2 * 132 + seg * 64;
#pragma unroll
    for (int k = 0; k < 16; ++k)
      reinterpret_cast<float4*>(dst)[k] = reinterpret_cast<const float4*>(src)[k];
  }
}

// ---------------- S = K^T Q, split-K=8 -> f32 partials ----------------
__global__ __launch_bounds__(256, 2) void attn_s(const u16* __restrict__ QP,
                                                 const u16* __restrict__ KP,
                                                 float* __restrict__ SP) {
  const int tid = threadIdx.x;
  const int lane = tid & 63;
  const int wv = tid >> 6, wm = wv >> 1, wn = wv & 1;
  const int lm = lane & 15, lq = lane >> 4;
  int mt = blockIdx.x;
  mt = (mt & 7) * 16 + (mt >> 3);  // 128 blocks, bijective
  const int b = mt >> 3, sp = mt & 7;

  f32x4 acc[4][4];
#pragma unroll
  for (int i = 0; i < 4; ++i)
#pragma unroll
    for (int j = 0; j < 4; ++j) acc[i][j] = f32x4{0.f, 0.f, 0.f, 0.f};

#pragma unroll
  for (int ksl = 0; ksl < 16; ++ksl) {
    const int ks = sp * 16 + ksl;
    bf16x8 af[4], bfr[4];
#pragma unroll
    for (int i = 0; i < 4; ++i)
      af[i] = *reinterpret_cast<const bf16x8*>(
          KP + (size_t)(((b * 128 + ks) * 8 + wm * 4 + i) * 64 + lane) * 8);
#pragma unroll
    for (int j = 0; j < 4; ++j)
      bfr[j] = *reinterpret_cast<const bf16x8*>(
          QP + (size_t)(((b * 128 + ks) * 8 + wn * 4 + j) * 64 + lane) * 8);
#pragma unroll
    for (int i = 0; i < 4; ++i)
#pragma unroll
      for (int j = 0; j < 4; ++j) acc[i][j] = mfma_bf16(af[i], bfr[j], acc[i][j]);
  }

  float* out = SP + (size_t)(b * 8 + sp) * 16384;
#pragma unroll
  for (int i = 0; i < 4; ++i)
#pragma unroll
    for (int j = 0; j < 4; ++j)
#pragma unroll
      for (int r = 0; r < 4; ++r)
        out[(wm * 64 + i * 16 + lq * 4 + r) * 128 + wn * 64 + j * 16 + lm] =
            acc[i][j][r];
}

// ---------------- fused: reduce partials + softmax + M = Pspe@A + pack M ----
__global__ __launch_bounds__(256, 1) void attn_rm(const float* __restrict__ SP,
                                                  const float* __restrict__ Pspe,
                                                  u16* __restrict__ Mpack) {
  __shared__ float Sf[128 * 129];  // 66048 B
  __shared__ u16 AT[128 * 136];    // 34816 B
  const int b = blockIdx.x;
  const int tid = threadIdx.x;
  const int lane = tid & 63;
  const int wv = tid >> 6, wm = wv >> 1, wn = wv & 1;
  const int lm = lane & 15, lq = lane >> 4;

  // reduce 8 split-K partials -> Sf (scaled)
#pragma unroll
  for (int it = 0; it < 64; ++it) {
    int id = it * 256 + tid;
    int rl = id >> 7, d = id & 127;
    const float* p = SP + (size_t)b * 8 * 16384 + (size_t)rl * 128 + d;
    float s = 0.f;
#pragma unroll
    for (int sp = 0; sp < 8; ++sp) s += p[(size_t)sp * 16384];
    Sf[rl * 129 + d] = s * 0.015625f;  // /sqrt(4096)
  }
  __syncthreads();

  // softmax over d per row c; write normalized A^T bf16 into AT[d][c]
  {
    int c = tid >> 1, hf = tid & 1;
    float* row = Sf + c * 129 + hf * 64;
    float mx = -3.4e38f;
#pragma unroll
    for (int k = 0; k < 64; ++k) mx = fmaxf(mx, row[k]);
    mx = fmaxf(mx, __shfl_xor(mx, 1));
    float s = 0.f;
#pragma unroll
    for (int k = 0; k < 64; ++k) {
      float e = __expf(row[k] - mx);
      row[k] = e;
      s += e;
    }
    s += __shfl_xor(s, 1);
    float inv = 1.0f / s;
#pragma unroll
    for (int k = 0; k < 64; ++k) AT[(hf * 64 + k) * 136 + c] = f2bf(row[k] * inv);
  }
  __syncthreads();

  // M = Pspe @ A : A-op P[c][e] (f32->bf16), B-op AT[d][e]
  f32x4 acc2[4][4];
#pragma unroll
  for (int i = 0; i < 4; ++i)
#pragma unroll
    for (int j = 0; j < 4; ++j) acc2[i][j] = f32x4{0.f, 0.f, 0.f, 0.f};
  const float* P = Pspe + (size_t)b * 128 * 128;
#pragma unroll
  for (int cc = 0; cc < 4; ++cc) {
    int e0 = cc * 32 + lq * 8;
    bf16x8 af[4], bfr[4];
#pragma unroll
    for (int i = 0; i < 4; ++i) {
      const float* p = P + (size_t)(wm * 64 + i * 16 + lm) * 128 + e0;
      union { u16 u[8]; bf16x8 v; } cvt;
#pragma unroll
      for (int e = 0; e < 8; ++e) cvt.u[e] = f2bf(p[e]);
      af[i] = cvt.v;
    }
#pragma unroll
    for (int j = 0; j < 4; ++j)
      bfr[j] = *reinterpret_cast<const bf16x8*>(AT + (wn * 64 + j * 16 + lm) * 136 + e0);
#pragma unroll
    for (int i = 0; i < 4; ++i)
#pragma unroll
      for (int j = 0; j < 4; ++j) acc2[i][j] = mfma_bf16(af[i], bfr[j], acc2[i][j]);
  }

  // write M transposed [d][c] into Ml (aliases Sf), then pack
  u16* Ml = reinterpret_cast<u16*>(Sf);  // [128][136]
#pragma unroll
  for (int i = 0; i < 4; ++i)
#pragma unroll
    for (int j = 0; j < 4; ++j)
#pragma unroll
      for (int r = 0; r < 4; ++r)
        Ml[(wn * 64 + j * 16 + lm) * 136 + (wm * 64 + i * 16 + lq * 4 + r)] =
            f2bf(acc2[i][j][r]);
  __syncthreads();

#pragma unroll
  for (int it = 0; it < 8; ++it) {
    int item = tid + it * 256;
    int l2 = item & 63, nb = (item >> 6) & 7, cc2 = item >> 9;
    int d = nb * 16 + (l2 & 15), c0 = cc2 * 32 + (l2 >> 4) * 8;
    *reinterpret_cast<uint4*>(Mpack + (size_t)b * 16384 + (size_t)item * 8) =
        *reinterpret_cast<const uint4*>(Ml + d * 136 + c0);
  }
}

// ---------------- F3 = V @ M -> Fp (padded) + zero Fp/Hp borders ----------
__global__ __launch_bounds__(256, 4) void f3_gemm(const u16* __restrict__ V,
                                                  const u16* __restrict__ Mpack,
                                                  u16* __restrict__ Fp,
                                                  u16* __restrict__ Hp) {
  const int tid = threadIdx.x;
  const int lane = tid & 63;
  const int wv = tid >> 6, wm = wv >> 1, wn = wv & 1;
  const int lm = lane & 15, lq = lane >> 4;
  const int bid = blockIdx.x;
  int mt = bid;
  mt = (mt & 7) * 64 + (mt >> 3);
  const int b = mt >> 5;
  const int yp = mt & 31;

  f32x4 acc[4][4];
#pragma unroll
  for (int i = 0; i < 4; ++i)
#pragma unroll
    for (int j = 0; j < 4; ++j) acc[i][j] = f32x4{0.f, 0.f, 0.f, 0.f};

#pragma unroll
  for (int cc = 0; cc < 4; ++cc) {
    int k0 = cc * 32 + lq * 8;
    bf16x8 af[4], bfr[4];
#pragma unroll
    for (int i = 0; i < 4; ++i)
      af[i] = *reinterpret_cast<const bf16x8*>(
          V + (size_t)(mt * 128 + wm * 64 + i * 16 + lm) * 128 + k0);
#pragma unroll
    for (int j = 0; j < 4; ++j)
      bfr[j] = *reinterpret_cast<const bf16x8*>(
          Mpack + (size_t)b * 16384 + (size_t)((cc * 8 + wn * 4 + j) * 64 + lane) * 8);
#pragma unroll
    for (int i = 0; i < 4; ++i)
#pragma unroll
      for (int j = 0; j < 4; ++j) acc[i][j] = mfma_bf16(af[i], bfr[j], acc[i][j]);
  }

  // zero borders of Fp and Hp
#pragma unroll
  for (int rep = 0; rep < 2; ++rep) {
    int p = bid * 32 + rep * 16 + (tid >> 4);
    if (p < 8320) {
      u16* buf = p < 4160 ? Fp : Hp;
      int q = p < 4160 ? p : p - 4160;
      int bb = q / 260, k = q % 260;
      int y, x;
      border_yx(k, y, x);
      *reinterpret_cast<uint4*>(buf + pidx(bb, y, x) + (tid & 15) * 8) =
          make_uint4(0u, 0u, 0u, 0u);
    }
  }

  __shared__ u16 T[128 * 136];
#pragma unroll
  for (int i = 0; i < 4; ++i)
#pragma unroll
    for (int j = 0; j < 4; ++j)
#pragma unroll
      for (int r = 0; r < 4; ++r)
        T[(wm * 64 + i * 16 + lq * 4 + r) * 136 + wn * 64 + j * 16 + lm] =
            f2bf(acc[i][j][r]);
  __syncthreads();
  int rr = tid >> 1, hf = tid & 1;
  int y = yp * 2 + (rr >> 6), x = rr & 63;
  const uint4* src = reinterpret_cast<const uint4*>(T + rr * 136 + hf * 64);
  uint4* dst = reinterpret_cast<uint4*>(Fp + pidx(b, y + 1, x + 1) + hf * 64);
#pragma unroll
  for (int k = 0; k < 8; ++k) dst[k] = src[k];
}

extern "C" void kernel_launch(void* const* d_in, const int* in_sizes, int n_in,
                              void* d_out, int out_size, void* d_ws, size_t ws_size,
                              hipStream_t stream) {
  const float* F_in = (const float*)d_in[0];
  const float* Pspe = (const float*)d_in[1];
  const float* q_w = (const float*)d_in[2];
  const float* q_b = (const float*)d_in[3];
  const float* k_w = (const float*)d_in[4];
  const float* k_b = (const float*)d_in[5];
  const float* v_w = (const float*)d_in[6];
  const float* v_b = (const float*)d_in[7];
  const float* f1_w = (const float*)d_in[8];
  const float* f1_b = (const float*)d_in[9];
  const float* f2_w = (const float*)d_in[10];
  const float* f2_b = (const float*)d_in[11];
  float* out = (float*)d_out;

  char* ws = (char*)d_ws;
  // padded buffer: 16*66*66*128*2 = 17,842,176 B; packed Q/K/V: 16,777,216 B each
  const size_t XPO = 0;
  const size_t QPO = 17842176;
  const size_t KPO = QPO + 16777216;
  const size_t VO  = KPO + 16777216;
  const size_t WPO = VO + 16777216;

  u16* Xp = (u16*)(ws + XPO);
  u16* QP = (u16*)(ws + QPO);
  u16* KP = (u16*)(ws + KPO);
  u16* V = (u16*)(ws + VO);
  u16* Wpk = (u16*)(ws + WPO);
  float* SP = (float*)(ws + XPO);            // partials alias Xp (dead)
  u16* Mpk = (u16*)(ws + KPO + 1179648);     // clear of Hp overrun
  u16* Fp = Xp;                              // padded F_ssm
  u16* Hp = QP;                              // padded hidden (overruns 1.04MB into KP head)

  pack_xw<<<1644, 256, 0, stream>>>(F_in, Xp, q_w, k_w, v_w, f1_w, f2_w, Wpk);
  convX<0><<<512, 256, 0, stream>>>(Xp, Wpk, q_b, k_b, v_b, QP, KP, V, nullptr,
                                    nullptr);
  attn_s<<<128, 256, 0, stream>>>(QP, KP, SP);
  attn_rm<<<16, 256, 0, stream>>>(SP, Pspe, Mpk);
  f3_gemm<<<512, 256, 0, stream>>>(V, Mpk, Fp, Hp);
  convX<1><<<512, 256, 0, stream>>>(Fp, Wpk + 3 * 147456, f1_b, nullptr, nullptr,
                                    Hp, nullptr, nullptr, nullptr, nullptr);
  convX<2><<<512, 256, 0, stream>>>(Hp, Wpk + 4 * 147456, f2_b, nullptr, nullptr,
                                    nullptr, nullptr, nullptr, out, Fp);
}

// Round 9
// 206.834 us; speedup vs baseline: 1.0497x; 1.0497x over previous
//
#include <hip/hip_runtime.h>
#include <cmath>

typedef unsigned short u16;
typedef __bf16 bf16x8 __attribute__((ext_vector_type(8)));
typedef float f32x4 __attribute__((ext_vector_type(4)));

__device__ __forceinline__ u16 f2bf(float f) {
  unsigned u = __float_as_uint(f);
  u += 0x7fffu + ((u >> 16) & 1u);
  return (u16)(u >> 16);
}
__device__ __forceinline__ float bf2f(u16 h) {
  return __uint_as_float(((unsigned)h) << 16);
}
__device__ __forceinline__ f32x4 mfma_bf16(bf16x8 a, bf16x8 b, f32x4 c) {
  return __builtin_amdgcn_mfma_f32_16x16x32_bf16(a, b, c, 0, 0, 0);
}
__device__ __forceinline__ float gelu_exact(float x) {
  return 0.5f * x * (1.0f + erff(x * 0.70710678118654752440f));
}

// B=16, C=128, H=64, W=64. Padded NHWC: [B][66][66][128], data at y+1,x+1.
__device__ __forceinline__ size_t pidx(int b, int y, int x) {
  return ((size_t)(b * 66 + y) * 66 + x) * 128;
}

__device__ __forceinline__ void border_yx(int k, int& y, int& x) {
  if (k < 66) { y = 0; x = k; }
  else if (k < 132) { y = 65; x = k - 66; }
  else if (k < 196) { y = k - 131; x = 0; }
  else { y = k - 195; x = 65; }
}

// ---- pack: X->padded NHWC bf16, weights->B-frag, X borders=0, WFB fold-pack
__global__ __launch_bounds__(256) void pack_xw(
    const float* __restrict__ Fin, u16* __restrict__ Xp,
    const float* __restrict__ w0, const float* __restrict__ w1,
    const float* __restrict__ w2, const float* __restrict__ w3,
    const float* __restrict__ w4, u16* __restrict__ Wpk,
    u16* __restrict__ WFB) {
  const int tid = threadIdx.x;
  const int bid = blockIdx.x;
  if (bid < 1024) {
    __shared__ float T[64 * 129];
    const int b = bid >> 6, y = bid & 63;
#pragma unroll
    for (int i = 0; i < 32; ++i) {
      int idx = tid + i * 256;
      int c = idx >> 6, x = idx & 63;
      T[x * 129 + c] = Fin[(size_t)(b * 128 + c) * 4096 + y * 64 + x];
    }
    __syncthreads();
#pragma unroll
    for (int i = 0; i < 4; ++i) {
      int chunk = tid + i * 256;
      int x = chunk >> 4;
      int c0 = (chunk & 15) * 8;
      u16 tmp[8];
#pragma unroll
      for (int e = 0; e < 8; ++e) tmp[e] = f2bf(T[x * 129 + c0 + e]);
      *reinterpret_cast<uint4*>(Xp + pidx(b, y + 1, x + 1) + c0) =
          *reinterpret_cast<const uint4*>(tmp);
    }
  } else if (bid < 1384) {
    int gid = (bid - 1024) * 256 + tid;  // 92160 total
    int lane = gid & 63;
    int nblk = (gid >> 6) & 7;
    int step = (gid >> 9) % 36;
    int conv = gid / (512 * 36);
    if (conv >= 5) return;
    const float* w = conv == 0 ? w0 : conv == 1 ? w1 : conv == 2 ? w2 : conv == 3 ? w3 : w4;
    int tap = step >> 2, cc = step & 3;
    int dy = tap / 3, dx = tap % 3;
    int co = nblk * 16 + (lane & 15);
    int ci0 = cc * 32 + (lane >> 4) * 8;
    u16 tmp[8];
#pragma unroll
    for (int e = 0; e < 8; ++e)
      tmp[e] = f2bf(w[((size_t)(co * 128 + ci0 + e) * 3 + dy) * 3 + dx]);
    size_t off = ((size_t)conv * 36 * 8 * 64 + (size_t)((step * 8 + nblk) * 64 + lane)) * 8;
    *reinterpret_cast<uint4*>(Wpk + off) = *reinterpret_cast<const uint4*>(tmp);
  } else if (bid < 1644) {
    // zero Xp borders: 4160 positions of 256B
    int p = (bid - 1384) * 16 + (tid >> 4);
    int b = p / 260, k = p % 260;
    int y, x;
    border_yx(k, y, x);
    *reinterpret_cast<uint4*>(Xp + pidx(b, y, x) + (tid & 15) * 8) =
        make_uint4(0u, 0u, 0u, 0u);
  } else {
    // WFB: Wv fold-pack (B-frag with n=ci, k=c): elem = v_w[c][ci][dy][dx]
    int gid = (bid - 1644) * 256 + tid;  // 18432 total
    int lane = gid & 63, nbci = (gid >> 6) & 7, stepf = gid >> 9;  // 0..35
    int tap = stepf >> 2, cc = stepf & 3;
    int dy = tap / 3, dx = tap % 3;
    int ci = nbci * 16 + (lane & 15);
    int c0 = cc * 32 + (lane >> 4) * 8;
    u16 tmp[8];
#pragma unroll
    for (int e = 0; e < 8; ++e)
      tmp[e] = f2bf(w2[(((size_t)(c0 + e) * 128 + ci) * 3 + dy) * 3 + dx]);
    *reinterpret_cast<uint4*>(WFB + ((size_t)(stepf * 8 + nbci) * 64 + lane) * 8) =
        *reinterpret_cast<const uint4*>(tmp);
  }
}

// ======== stage A tile from padded Xp: 4 rows x 66 x 128ch, XOR-swizzled ====
__device__ __forceinline__ void stageA(const u16* __restrict__ Xp, u16* Xs,
                                       int tid, int b, int y0p) {
#pragma unroll
  for (int i = 0; i < 17; ++i) {
    int j = i * 256 + tid;  // chunk 0..4223
    if (i == 16 && j >= 4224) break;
    int row = j >> 4, c16 = j & 15;
    int ys = row / 66, xs = row - ys * 66;
    uint4 val = *reinterpret_cast<const uint4*>(Xp + pidx(b, y0p + ys, xs) + c16 * 8);
    unsigned off = (unsigned)((row * 128 + c16 * 8) * 2) ^ (unsigned)((xs & 7) << 4);
    *reinterpret_cast<uint4*>(reinterpret_cast<char*>(Xs) + off) = val;
  }
}

// ---------------- conv3x3 implicit GEMM (r3-proven core) --------------------
// EPI 0: QK fused (acc[2]) -> fragment-packed QP,KP
// EPI 1: VM conv (per-batch folded weights+bias) -> padded Fp bf16
// EPI 2: f1 (gelu) -> padded Hp bf16
// EPI 3: f2 -> f32 NCHW + residual from padded Fp
template <int EPI>
__global__ __launch_bounds__(256, 2) void conv_t(
    const u16* __restrict__ Xin, const u16* __restrict__ Wb,
    const float* __restrict__ bias0, const float* __restrict__ bias1,
    u16* __restrict__ OA, u16* __restrict__ OB,
    float* __restrict__ OutF, const u16* __restrict__ Resid) {
  constexpr int NCV = (EPI == 0) ? 2 : 1;
  __shared__ alignas(16) u16 Xs[4 * 66 * 128];  // 67584 B
  const int tid = threadIdx.x;
  const int lane = tid & 63, wv = tid >> 6;
  const int wm = wv >> 1, wn = wv & 1;
  int mt = blockIdx.x;
  mt = (mt & 7) * 64 + (mt >> 3);  // 512 blocks, bijective XCD swizzle
  const int b = mt >> 5, yp = mt & 31;
  const int lm = lane & 15, lq = lane >> 4;

  stageA(Xin, Xs, tid, b, yp * 2);
  __syncthreads();

  f32x4 acc[NCV][4][4];
#pragma unroll
  for (int c = 0; c < NCV; ++c)
#pragma unroll
    for (int i = 0; i < 4; ++i)
#pragma unroll
      for (int j = 0; j < 4; ++j) acc[c][i][j] = f32x4{0.f, 0.f, 0.f, 0.f};

  const u16* WpC = (EPI == 1) ? Wb + (size_t)b * 147456 : Wb;
  const u16* wlane = WpC + (size_t)lane * 8;

#pragma unroll 1
  for (int tap = 0; tap < 9; ++tap) {
    const int dy = (tap * 11) >> 5;  // tap/3
    const int dx = tap - dy * 3;
#pragma unroll
    for (int cc = 0; cc < 4; ++cc) {
      const int step = tap * 4 + cc;
      bf16x8 af[4];
#pragma unroll
      for (int i = 0; i < 4; ++i) {
        int xs = i * 16 + lm + dx;
        unsigned off = (unsigned)((((wm + dy) * 66 + xs) * 128 + cc * 32 + lq * 8) * 2) ^
                       (unsigned)((xs & 7) << 4);
        af[i] = *reinterpret_cast<const bf16x8*>(
            reinterpret_cast<const char*>(Xs) + off);
      }
#pragma unroll
      for (int cv = 0; cv < NCV; ++cv) {
        bf16x8 bfr[4];
#pragma unroll
        for (int j = 0; j < 4; ++j)
          bfr[j] = *reinterpret_cast<const bf16x8*>(
              wlane + (size_t)cv * 147456 + (size_t)((step * 8 + wn * 4 + j) * 64) * 8);
#pragma unroll
        for (int i = 0; i < 4; ++i)
#pragma unroll
          for (int j = 0; j < 4; ++j)
            acc[cv][i][j] = mfma_bf16(af[i], bfr[j], acc[cv][i][j]);
      }
    }
  }

  __syncthreads();  // Xs dead; reuse for epilogues

  if (EPI == 0) {
    u16* T = Xs;  // [128][136]
#pragma unroll 1
    for (int cv = 0; cv < 2; ++cv) {
      const float* bias = cv == 0 ? bias0 : bias1;
      u16* OutB = cv == 0 ? OA : OB;
#pragma unroll
      for (int i = 0; i < 4; ++i)
#pragma unroll
        for (int j = 0; j < 4; ++j) {
          int n = wn * 64 + j * 16 + lm;
          float bs = bias[n];
#pragma unroll
          for (int r = 0; r < 4; ++r) {
            int m = wm * 64 + i * 16 + lq * 4 + r;
            T[n * 136 + m] = f2bf(acc[cv][i][j][r] + bs);
          }
        }
      __syncthreads();
#pragma unroll
      for (int it = 0; it < 8; ++it) {
        int item = tid + it * 256;
        int l = item & 63, cb = (item >> 6) & 7, ksl = item >> 9;
        int c = cb * 16 + (l & 15);
        int mloc = ksl * 32 + (l >> 4) * 8;
        int ks = yp * 4 + ksl;
        *reinterpret_cast<uint4*>(
            OutB + (size_t)(((b * 128 + ks) * 8 + cb) * 64 + l) * 8) =
            *reinterpret_cast<const uint4*>(T + c * 136 + mloc);
      }
      __syncthreads();
    }
  } else if (EPI == 1 || EPI == 2) {
    u16* T = Xs;  // [128][136]
#pragma unroll
    for (int i = 0; i < 4; ++i)
#pragma unroll
      for (int j = 0; j < 4; ++j) {
        int n = wn * 64 + j * 16 + lm;
        float bs = (EPI == 1) ? bias0[b * 128 + n] : bias0[n];
#pragma unroll
        for (int r = 0; r < 4; ++r) {
          int m = wm * 64 + i * 16 + lq * 4 + r;
          float v = acc[0][i][j][r] + bs;
          if (EPI == 2) v = gelu_exact(v);
          T[m * 136 + n] = f2bf(v);
        }
      }
    __syncthreads();
    int rr = tid >> 1, hf = tid & 1;
    int y = yp * 2 + (rr >> 6), x = rr & 63;
    const uint4* src = reinterpret_cast<const uint4*>(T + rr * 136 + hf * 64);
    uint4* dst = reinterpret_cast<uint4*>(OA + pidx(b, y + 1, x + 1) + hf * 64);
#pragma unroll
    for (int k = 0; k < 8; ++k) dst[k] = src[k];
  } else {
    // f2: single-pass f32 transpose [128][132] = 67584B + residual
    float* Tf = reinterpret_cast<float*>(Xs);
#pragma unroll
    for (int i = 0; i < 4; ++i)
#pragma unroll
      for (int j = 0; j < 4; ++j) {
        int n = wn * 64 + j * 16 + lm;
        float bs = bias0[n];
        int m0 = wm * 64 + i * 16 + lq * 4;
        int y = yp * 2 + (m0 >> 6), x = m0 & 63;
        const u16* rp = Resid + pidx(b, y + 1, x + 1) + n;
#pragma unroll
        for (int r = 0; r < 4; ++r)
          Tf[n * 132 + m0 + r] = acc[0][i][j][r] + bs + bf2f(rp[r * 128]);
      }
    __syncthreads();
    int n2 = tid >> 1, seg = tid & 1;
    float* dst = OutF + ((size_t)(b * 128 + n2) * 4096 + yp * 128 + seg * 64);
    const float* src = Tf + n2 * 132 + seg * 64;
#pragma unroll
    for (int k = 0; k < 16; ++k)
      reinterpret_cast<float4*>(dst)[k] = reinterpret_cast<const float4*>(src)[k];
  }
}

// ---------------- S = K^T Q, split-K=8 -> f32 partials ----------------
__global__ __launch_bounds__(256, 2) void attn_s(const u16* __restrict__ QP,
                                                 const u16* __restrict__ KP,
                                                 float* __restrict__ SP) {
  const int tid = threadIdx.x;
  const int lane = tid & 63;
  const int wv = tid >> 6, wm = wv >> 1, wn = wv & 1;
  const int lm = lane & 15, lq = lane >> 4;
  int mt = blockIdx.x;
  mt = (mt & 7) * 16 + (mt >> 3);  // 128 blocks, bijective
  const int b = mt >> 3, sp = mt & 7;

  f32x4 acc[4][4];
#pragma unroll
  for (int i = 0; i < 4; ++i)
#pragma unroll
    for (int j = 0; j < 4; ++j) acc[i][j] = f32x4{0.f, 0.f, 0.f, 0.f};

#pragma unroll
  for (int ksl = 0; ksl < 16; ++ksl) {
    const int ks = sp * 16 + ksl;
    bf16x8 af[4], bfr[4];
#pragma unroll
    for (int i = 0; i < 4; ++i)
      af[i] = *reinterpret_cast<const bf16x8*>(
          KP + (size_t)(((b * 128 + ks) * 8 + wm * 4 + i) * 64 + lane) * 8);
#pragma unroll
    for (int j = 0; j < 4; ++j)
      bfr[j] = *reinterpret_cast<const bf16x8*>(
          QP + (size_t)(((b * 128 + ks) * 8 + wn * 4 + j) * 64 + lane) * 8);
#pragma unroll
    for (int i = 0; i < 4; ++i)
#pragma unroll
      for (int j = 0; j < 4; ++j) acc[i][j] = mfma_bf16(af[i], bfr[j], acc[i][j]);
  }

  float* out = SP + (size_t)(b * 8 + sp) * 16384;
#pragma unroll
  for (int i = 0; i < 4; ++i)
#pragma unroll
    for (int j = 0; j < 4; ++j)
#pragma unroll
      for (int r = 0; r < 4; ++r)
        out[(wm * 64 + i * 16 + lq * 4 + r) * 128 + wn * 64 + j * 16 + lm] =
            acc[i][j][r];
}

// ---- fused: reduce partials + softmax + M=Pspe@A + pack M^T + fold bias ----
__global__ __launch_bounds__(256, 1) void attn_rm(const float* __restrict__ SP,
                                                  const float* __restrict__ Pspe,
                                                  const float* __restrict__ vb,
                                                  u16* __restrict__ Mpack,
                                                  float* __restrict__ bfold) {
  __shared__ float Sf[128 * 129];  // 66048 B
  __shared__ u16 AT[128 * 136];    // 34816 B
  const int b = blockIdx.x;
  const int tid = threadIdx.x;
  const int lane = tid & 63;
  const int wv = tid >> 6, wm = wv >> 1, wn = wv & 1;
  const int lm = lane & 15, lq = lane >> 4;

#pragma unroll
  for (int it = 0; it < 64; ++it) {
    int id = it * 256 + tid;
    int rl = id >> 7, d = id & 127;
    const float* p = SP + (size_t)b * 8 * 16384 + (size_t)rl * 128 + d;
    float s = 0.f;
#pragma unroll
    for (int sp = 0; sp < 8; ++sp) s += p[(size_t)sp * 16384];
    Sf[rl * 129 + d] = s * 0.015625f;  // /sqrt(4096)
  }
  __syncthreads();

  {
    int c = tid >> 1, hf = tid & 1;
    float* row = Sf + c * 129 + hf * 64;
    float mx = -3.4e38f;
#pragma unroll
    for (int k = 0; k < 64; ++k) mx = fmaxf(mx, row[k]);
    mx = fmaxf(mx, __shfl_xor(mx, 1));
    float s = 0.f;
#pragma unroll
    for (int k = 0; k < 64; ++k) {
      float e = __expf(row[k] - mx);
      row[k] = e;
      s += e;
    }
    s += __shfl_xor(s, 1);
    float inv = 1.0f / s;
#pragma unroll
    for (int k = 0; k < 64; ++k) AT[(hf * 64 + k) * 136 + c] = f2bf(row[k] * inv);
  }
  __syncthreads();

  // M = Pspe @ A
  f32x4 acc2[4][4];
#pragma unroll
  for (int i = 0; i < 4; ++i)
#pragma unroll
    for (int j = 0; j < 4; ++j) acc2[i][j] = f32x4{0.f, 0.f, 0.f, 0.f};
  const float* P = Pspe + (size_t)b * 128 * 128;
#pragma unroll
  for (int cc = 0; cc < 4; ++cc) {
    int e0 = cc * 32 + lq * 8;
    bf16x8 af[4], bfr[4];
#pragma unroll
    for (int i = 0; i < 4; ++i) {
      const float* p = P + (size_t)(wm * 64 + i * 16 + lm) * 128 + e0;
      union { u16 u[8]; bf16x8 v; } cvt;
#pragma unroll
      for (int e = 0; e < 8; ++e) cvt.u[e] = f2bf(p[e]);
      af[i] = cvt.v;
    }
#pragma unroll
    for (int j = 0; j < 4; ++j)
      bfr[j] = *reinterpret_cast<const bf16x8*>(AT + (wn * 64 + j * 16 + lm) * 136 + e0);
#pragma unroll
    for (int i = 0; i < 4; ++i)
#pragma unroll
      for (int j = 0; j < 4; ++j) acc2[i][j] = mfma_bf16(af[i], bfr[j], acc2[i][j]);
  }

  // M^T [d][c] into Ml (aliases Sf)
  u16* Ml = reinterpret_cast<u16*>(Sf);  // [128][136]
#pragma unroll
  for (int i = 0; i < 4; ++i)
#pragma unroll
    for (int j = 0; j < 4; ++j)
#pragma unroll
      for (int r = 0; r < 4; ++r)
        Ml[(wn * 64 + j * 16 + lm) * 136 + (wm * 64 + i * 16 + lq * 4 + r)] =
            f2bf(acc2[i][j][r]);
  __syncthreads();

  // pack M^T as MFMA A-fragments (m=d, k=c)
#pragma unroll
  for (int it = 0; it < 8; ++it) {
    int item = tid + it * 256;
    int l2 = item & 63, nb = (item >> 6) & 7, cc2 = item >> 9;
    int d = nb * 16 + (l2 & 15), c0 = cc2 * 32 + (l2 >> 4) * 8;
    *reinterpret_cast<uint4*>(Mpack + (size_t)b * 16384 + (size_t)item * 8) =
        *reinterpret_cast<const uint4*>(Ml + d * 136 + c0);
  }
  // folded bias: b'[d] = sum_c vb[c] * M[c][d]
  if (tid < 128) {
    float s = 0.f;
    for (int c = 0; c < 128; ++c) s += vb[c] * bf2f(Ml[tid * 136 + c]);
    bfold[b * 128 + tid] = s;
  }
}

// ---- wfold: W'^T[d][kr] = sum_c M^T[d][c] Wv[c][kr]; pack to conv B-frags ----
// grid 144 = b*9 + tap. Also zeroes Fp/Hp borders.
__global__ __launch_bounds__(256, 2) void wfold(const u16* __restrict__ Mpk,
                                                const u16* __restrict__ WFB,
                                                u16* __restrict__ Wfold,
                                                u16* __restrict__ Fp,
                                                u16* __restrict__ Hp) {
  __shared__ u16 T[128 * 136];
  const int tid = threadIdx.x;
  const int lane = tid & 63, wv = tid >> 6;
  const int wm = wv >> 1, wn = wv & 1;
  const int lm = lane & 15, lq = lane >> 4;
  const int b = blockIdx.x / 9, tap = blockIdx.x % 9;

  f32x4 acc[4][4];
#pragma unroll
  for (int i = 0; i < 4; ++i)
#pragma unroll
    for (int j = 0; j < 4; ++j) acc[i][j] = f32x4{0.f, 0.f, 0.f, 0.f};

#pragma unroll
  for (int cc = 0; cc < 4; ++cc) {
    bf16x8 af[4], bfr[4];
#pragma unroll
    for (int i = 0; i < 4; ++i)
      af[i] = *reinterpret_cast<const bf16x8*>(
          Mpk + (size_t)b * 16384 + (size_t)(((cc * 8 + wm * 4 + i) * 64) + lane) * 8);
#pragma unroll
    for (int j = 0; j < 4; ++j)
      bfr[j] = *reinterpret_cast<const bf16x8*>(
          WFB + (size_t)(((tap * 4 + cc) * 8 + wn * 4 + j) * 64 + lane) * 8);
#pragma unroll
    for (int i = 0; i < 4; ++i)
#pragma unroll
      for (int j = 0; j < 4; ++j) acc[i][j] = mfma_bf16(af[i], bfr[j], acc[i][j]);
  }

  // zero Fp/Hp borders: 2*4160 positions * 16 chunks = 133120 uint4 writes
#pragma unroll
  for (int it = 0; it < 4; ++it) {
    int idx = (blockIdx.x * 256 + tid) + it * 36864;
    if (idx < 133120) {
      int p = idx >> 4, c16 = idx & 15;
      u16* buf = p < 4160 ? Fp : Hp;
      int q = p < 4160 ? p : p - 4160;
      int bb = q / 260, k = q % 260;
      int y, x;
      border_yx(k, y, x);
      *reinterpret_cast<uint4*>(buf + pidx(bb, y, x) + c16 * 8) =
          make_uint4(0u, 0u, 0u, 0u);
    }
  }

  // T[d][ci] = W'^T (natural orientation: row=d, col=ci)
#pragma unroll
  for (int i = 0; i < 4; ++i)
#pragma unroll
    for (int j = 0; j < 4; ++j)
#pragma unroll
      for (int r = 0; r < 4; ++r)
        T[(wm * 64 + i * 16 + lq * 4 + r) * 136 + wn * 64 + j * 16 + lm] =
            f2bf(acc[i][j][r]);
  __syncthreads();

  // pack into conv B-frag layout: [step=tap*4+cc2][nb=d>>4][L][e]
#pragma unroll
  for (int it = 0; it < 8; ++it) {
    int item = tid + it * 256;  // 0..2047
    int L = item & 63, nb = (item >> 6) & 7, cc2 = item >> 9;
    int d = nb * 16 + (L & 15);
    int ci0 = cc2 * 32 + (L >> 4) * 8;
    *reinterpret_cast<uint4*>(
        Wfold + (size_t)b * 147456 +
        ((size_t)(((tap * 4 + cc2) * 8 + nb) * 64 + L)) * 8) =
        *reinterpret_cast<const uint4*>(T + d * 136 + ci0);
  }
}

extern "C" void kernel_launch(void* const* d_in, const int* in_sizes, int n_in,
                              void* d_out, int out_size, void* d_ws, size_t ws_size,
                              hipStream_t stream) {
  const float* F_in = (const float*)d_in[0];
  const float* Pspe = (const float*)d_in[1];
  const float* q_w = (const float*)d_in[2];
  const float* q_b = (const float*)d_in[3];
  const float* k_w = (const float*)d_in[4];
  const float* k_b = (const float*)d_in[5];
  const float* v_w = (const float*)d_in[6];
  const float* v_b = (const float*)d_in[7];
  const float* f1_w = (const float*)d_in[8];
  const float* f1_b = (const float*)d_in[9];
  const float* f2_w = (const float*)d_in[10];
  const float* f2_b = (const float*)d_in[11];
  float* out = (float*)d_out;

  char* ws = (char*)d_ws;
  const size_t XPO = 0;                    // Xp 17,842,176 (alive until conv_vm)
  const size_t QPO = 17842176;             // QP; later Fp (17.84MB, overruns into KP head)
  const size_t KPO = 34619392;             // KP
  const size_t HPO = 35684352;             // Hp 17,842,176 (after Fp; KP dead)
  const size_t SPO = 53526528;             // SP 8,388,608; later Wfold (4.72MB)
  const size_t MPO = 61915136;             // Mpk 524,288
  const size_t BFO = 62439424;             // bfold 8,192
  const size_t WPO = 62447616;             // Wpk 1,474,560
  const size_t WFBO = 63922176;            // WFB 294,912 -> ends 64,217,088

  u16* Xp = (u16*)(ws + XPO);
  u16* QP = (u16*)(ws + QPO);
  u16* KP = (u16*)(ws + KPO);
  u16* Hp = (u16*)(ws + HPO);
  float* SP = (float*)(ws + SPO);
  u16* Wfold = (u16*)(ws + SPO);           // aliases SP (dead after attn_rm)
  u16* Mpk = (u16*)(ws + MPO);
  float* bfold = (float*)(ws + BFO);
  u16* Wpk = (u16*)(ws + WPO);
  u16* WFB = (u16*)(ws + WFBO);
  u16* Fp = QP;                            // padded F3 (QP dead after attn_s)

  pack_xw<<<1716, 256, 0, stream>>>(F_in, Xp, q_w, k_w, v_w, f1_w, f2_w, Wpk, WFB);
  conv_t<0><<<512, 256, 0, stream>>>(Xp, Wpk, q_b, k_b, QP, KP, nullptr, nullptr);
  attn_s<<<128, 256, 0, stream>>>(QP, KP, SP);
  attn_rm<<<16, 256, 0, stream>>>(SP, Pspe, v_b, Mpk, bfold);
  wfold<<<144, 256, 0, stream>>>(Mpk, WFB, Wfold, Fp, Hp);
  conv_t<1><<<512, 256, 0, stream>>>(Xp, Wfold, bfold, nullptr, Fp, nullptr,
                                     nullptr, nullptr);
  conv_t<2><<<512, 256, 0, stream>>>(Fp, Wpk + 3 * 147456, f1_b, nullptr, Hp,
                                     nullptr, nullptr, nullptr);
  conv_t<3><<<512, 256, 0, stream>>>(Hp, Wpk + 4 * 147456, f2_b, nullptr, nullptr,
                                     nullptr, out, Fp);
}

// Round 10
// 177.556 us; speedup vs baseline: 1.2228x; 1.1649x over previous
//
#include <hip/hip_runtime.h>
#include <cmath>

typedef unsigned short u16;
typedef __bf16 bf16x8 __attribute__((ext_vector_type(8)));
typedef float f32x4 __attribute__((ext_vector_type(4)));

__device__ __forceinline__ u16 f2bf(float f) {
  unsigned u = __float_as_uint(f);
  u += 0x7fffu + ((u >> 16) & 1u);
  return (u16)(u >> 16);
}
__device__ __forceinline__ float bf2f(u16 h) {
  return __uint_as_float(((unsigned)h) << 16);
}
__device__ __forceinline__ f32x4 mfma_bf16(bf16x8 a, bf16x8 b, f32x4 c) {
  return __builtin_amdgcn_mfma_f32_16x16x32_bf16(a, b, c, 0, 0, 0);
}
__device__ __forceinline__ float gelu_exact(float x) {
  return 0.5f * x * (1.0f + erff(x * 0.70710678118654752440f));
}

// B=16, C=128, H=64, W=64, HW=4096, NPOS=65536

// ---------------- merged pack: X (NCHW f32 -> NHWC bf16) + weights ----------
__global__ __launch_bounds__(256) void pack_xw(
    const float* __restrict__ Fin, u16* __restrict__ X,
    const float* __restrict__ w0, const float* __restrict__ w1,
    const float* __restrict__ w2, const float* __restrict__ w3,
    const float* __restrict__ w4, u16* __restrict__ Wpk) {
  __shared__ float T[64 * 129];
  const int tid = threadIdx.x;
  if (blockIdx.x < 1024) {
    const int b = blockIdx.x >> 6, y = blockIdx.x & 63;
#pragma unroll
    for (int i = 0; i < 32; ++i) {
      int idx = tid + i * 256;
      int c = idx >> 6, x = idx & 63;
      T[x * 129 + c] = Fin[(size_t)(b * 128 + c) * 4096 + y * 64 + x];
    }
    __syncthreads();
#pragma unroll
    for (int i = 0; i < 4; ++i) {
      int chunk = tid + i * 256;
      int x = chunk >> 4;
      int c0 = (chunk & 15) * 8;
      u16 tmp[8];
#pragma unroll
      for (int e = 0; e < 8; ++e) tmp[e] = f2bf(T[x * 129 + c0 + e]);
      *reinterpret_cast<uint4*>(X + ((size_t)((b * 64 + y) * 64 + x) * 128 + c0)) =
          *reinterpret_cast<const uint4*>(tmp);
    }
  } else {
    int gid = (blockIdx.x - 1024) * 256 + tid;  // 92160 total
    int lane = gid & 63;
    int nblk = (gid >> 6) & 7;
    int step = (gid >> 9) % 36;
    int conv = gid / (512 * 36);
    if (conv >= 5) return;
    const float* w = conv == 0 ? w0 : conv == 1 ? w1 : conv == 2 ? w2 : conv == 3 ? w3 : w4;
    int tap = step >> 2, cc = step & 3;
    int dy = tap / 3, dx = tap % 3;
    int co = nblk * 16 + (lane & 15);
    int ci0 = cc * 32 + (lane >> 4) * 8;
    u16 tmp[8];
#pragma unroll
    for (int e = 0; e < 8; ++e)
      tmp[e] = f2bf(w[((size_t)(co * 128 + ci0 + e) * 3 + dy) * 3 + dx]);
    size_t off = ((size_t)conv * 36 * 8 * 64 + (size_t)((step * 8 + nblk) * 64 + lane)) * 8;
    *reinterpret_cast<uint4*>(Wpk + off) = *reinterpret_cast<const uint4*>(tmp);
  }
}

// ======== shared staging: rows y0-1..y0+2, x-halo, XOR-swizzled ========
__device__ __forceinline__ void stage_tile(const u16* __restrict__ Xin, u16* Xs,
                                           int tid, int b, int y0) {
#pragma unroll
  for (int i = 0; i < 16; ++i) {
    int j = tid + i * 256;
    int row = j >> 4;
    int c16 = j & 15;
    int ys = row >> 6, x = row & 63;
    int ysrc = y0 - 1 + ys;
    uint4 val = make_uint4(0u, 0u, 0u, 0u);
    if ((unsigned)ysrc < 64u)
      val = *reinterpret_cast<const uint4*>(
          Xin + ((size_t)((b * 64 + ysrc) * 64 + x) * 128 + c16 * 8));
    int xs = x + 1;
    unsigned off = (unsigned)(((ys * 66 + xs) * 128 + c16 * 8) * 2) ^
                   (unsigned)((xs & 7) << 4);
    *reinterpret_cast<uint4*>(reinterpret_cast<char*>(Xs) + off) = val;
  }
  if (tid < 128) {
    int ys = tid >> 5, side = (tid >> 4) & 1, c16 = tid & 15;
    int xs = side ? 65 : 0;
    unsigned off = (unsigned)(((ys * 66 + xs) * 128 + c16 * 8) * 2) ^
                   (unsigned)((xs & 7) << 4);
    *reinterpret_cast<uint4*>(reinterpret_cast<char*>(Xs) + off) =
        make_uint4(0u, 0u, 0u, 0u);
  }
}

// ---------------- fused QKV conv3x3, N-split tile M128xN64, pipelined -------
__global__ __launch_bounds__(256, 2) void conv_qkv(
    const u16* __restrict__ Xin, const u16* __restrict__ Wp,
    const float* __restrict__ qb, const float* __restrict__ kb,
    const float* __restrict__ vb, u16* __restrict__ QP,
    u16* __restrict__ KP, u16* __restrict__ Vout) {
  __shared__ alignas(16) u16 Xs[4 * 66 * 128];
  const int tid = threadIdx.x;
  const int lane = tid & 63;
  const int wv = tid >> 6;
  const int wm = wv >> 1, wn = wv & 1;
  int mt = blockIdx.x;
  mt = (mt & 7) * 128 + (mt >> 3);  // 1024 blocks, bijective XCD swizzle
  const int b = mt >> 6;
  const int r = mt & 63;
  const int yp = r >> 1;      // y-pair 0..31
  const int nh = r & 1;       // N half
  const int y0 = yp * 2;

  stage_tile(Xin, Xs, tid, b, y0);
  __syncthreads();

  f32x4 acc[3][4][2];
#pragma unroll
  for (int c = 0; c < 3; ++c)
#pragma unroll
    for (int i = 0; i < 4; ++i)
#pragma unroll
      for (int j = 0; j < 2; ++j) acc[c][i][j] = f32x4{0.f, 0.f, 0.f, 0.f};

  const int lm = lane & 15, lq = lane >> 4;
  const u16* wb = Wp + (size_t)(((nh * 4 + wn * 2) * 64) + lane) * 8;

  auto loada = [&](bf16x8 (&d)[4], int s) {
    int tap = s >> 2, cc = s & 3;
    int dy = (tap * 11) >> 5;
    int dx = tap - dy * 3;
    int row = (wm + dy) * 66;
#pragma unroll
    for (int i = 0; i < 4; ++i) {
      int xs = i * 16 + lm + dx;
      unsigned off = (unsigned)(((row + xs) * 128 + cc * 32 + lq * 8) * 2) ^
                     (unsigned)((xs & 7) << 4);
      d[i] = *reinterpret_cast<const bf16x8*>(reinterpret_cast<const char*>(Xs) + off);
    }
  };
  auto loadb = [&](bf16x8 (&d)[6], int s) {
#pragma unroll
    for (int cv = 0; cv < 3; ++cv)
#pragma unroll
      for (int j = 0; j < 2; ++j)
        d[cv * 2 + j] = *reinterpret_cast<const bf16x8*>(
            wb + (size_t)cv * 147456 + (size_t)s * 4096 + j * 512);
  };
  auto step = [&](bf16x8 (&a)[4], bf16x8 (&bm)[6]) {
#pragma unroll
    for (int cv = 0; cv < 3; ++cv)
#pragma unroll
      for (int i = 0; i < 4; ++i)
#pragma unroll
        for (int j = 0; j < 2; ++j)
          acc[cv][i][j] = mfma_bf16(a[i], bm[cv * 2 + j], acc[cv][i][j]);
  };

  bf16x8 a0[4], a1[4], b0[6], b1[6];
  loada(a0, 0);
  loadb(b0, 0);
#pragma unroll 1
  for (int s = 0; s < 36; s += 2) {
    loada(a1, s + 1);
    loadb(b1, s + 1);
    step(a0, b0);
    if (s + 2 < 36) {
      loada(a0, s + 2);
      loadb(b0, s + 2);
    }
    step(a1, b1);
  }

  __syncthreads();  // Xs dead; reuse for epilogues

  // ---- Q, K: fragment-packed epilogue ----
  u16* T = Xs;  // [64][136]
#pragma unroll
  for (int cv = 0; cv < 2; ++cv) {
    const float* bias = cv == 0 ? qb : kb;
    u16* OutB = cv == 0 ? QP : KP;
#pragma unroll
    for (int i = 0; i < 4; ++i)
#pragma unroll
      for (int j = 0; j < 2; ++j) {
        int nloc = wn * 32 + j * 16 + lm;
        float bs = bias[nh * 64 + nloc];
#pragma unroll
        for (int rr = 0; rr < 4; ++rr) {
          int m = wm * 64 + i * 16 + lq * 4 + rr;
          T[nloc * 136 + m] = f2bf(acc[cv][i][j][rr] + bs);
        }
      }
    __syncthreads();
#pragma unroll
    for (int it = 0; it < 4; ++it) {
      int item = tid + it * 256;  // 0..1023
      int l = item & 63, cbl = (item >> 6) & 3, ksl = item >> 8;
      int c = cbl * 16 + (l & 15);
      int mloc = ksl * 32 + (l >> 4) * 8;
      int ks = yp * 4 + ksl, cb = nh * 4 + cbl;
      *reinterpret_cast<uint4*>(
          OutB + (size_t)(((b * 128 + ks) * 8 + cb) * 64 + l) * 8) =
          *reinterpret_cast<const uint4*>(T + c * 136 + mloc);
    }
    __syncthreads();
  }

  // ---- V: natural [pos][ch] ----
  u16* Tv = Xs;  // [128][72]
#pragma unroll
  for (int i = 0; i < 4; ++i)
#pragma unroll
    for (int j = 0; j < 2; ++j) {
      int nloc = wn * 32 + j * 16 + lm;
      float bs = vb[nh * 64 + nloc];
#pragma unroll
      for (int rr = 0; rr < 4; ++rr) {
        int m = wm * 64 + i * 16 + lq * 4 + rr;
        Tv[m * 72 + nloc] = f2bf(acc[2][i][j][rr] + bs);
      }
    }
  __syncthreads();
  {
    int rr = tid >> 1, q = tid & 1;
    const uint4* src = reinterpret_cast<const uint4*>(Tv + rr * 72 + q * 32);
    uint4* dst = reinterpret_cast<uint4*>(
        Vout + ((size_t)((b * 32 + yp) * 128 + rr) * 128 + nh * 64 + q * 32));
#pragma unroll
    for (int k = 0; k < 4; ++k) dst[k] = src[k];
  }
}

// ---------------- FFN convs (r4 core), pipelined ----------------
// MODE 1: f1' (per-batch folded weights, gelu -> natural bf16 Hid)
// MODE 3: f2' (f32 NCHW out + inline V@M residual)
template <int MODE>
__global__ __launch_bounds__(256, 2) void conv_gemm(
    const u16* __restrict__ Xin, const u16* __restrict__ Wp,
    const float* __restrict__ bias, u16* __restrict__ OutB,
    float* __restrict__ OutF, const u16* __restrict__ Vin,
    const u16* __restrict__ Mpk) {
  __shared__ alignas(16) u16 Xs[4 * 66 * 128];
  const int tid = threadIdx.x;
  const int lane = tid & 63;
  const int wv = tid >> 6;
  const int wm = wv >> 1, wn = wv & 1;
  int mt = blockIdx.x;
  mt = (mt & 7) * 64 + (mt >> 3);
  const int b = mt >> 5;
  const int y0 = (mt & 31) * 2;

  stage_tile(Xin, Xs, tid, b, y0);
  __syncthreads();

  f32x4 acc[4][4];
#pragma unroll
  for (int i = 0; i < 4; ++i)
#pragma unroll
    for (int j = 0; j < 4; ++j) acc[i][j] = f32x4{0.f, 0.f, 0.f, 0.f};

  const int lm = lane & 15, lq = lane >> 4;
  const u16* wb = Wp + (MODE == 1 ? (size_t)b * 147456 : (size_t)0) +
                  (size_t)((wn * 4 * 64) + lane) * 8;

  auto loada = [&](bf16x8 (&d)[4], int s) {
    int tap = s >> 2, cc = s & 3;
    int dy = (tap * 11) >> 5;
    int dx = tap - dy * 3;
    int row = (wm + dy) * 66;
#pragma unroll
    for (int i = 0; i < 4; ++i) {
      int xs = i * 16 + lm + dx;
      unsigned off = (unsigned)(((row + xs) * 128 + cc * 32 + lq * 8) * 2) ^
                     (unsigned)((xs & 7) << 4);
      d[i] = *reinterpret_cast<const bf16x8*>(reinterpret_cast<const char*>(Xs) + off);
    }
  };
  auto loadb = [&](bf16x8 (&d)[4], int s) {
#pragma unroll
    for (int j = 0; j < 4; ++j)
      d[j] = *reinterpret_cast<const bf16x8*>(wb + (size_t)s * 4096 + j * 512);
  };
  auto step = [&](bf16x8 (&a)[4], bf16x8 (&bm)[4]) {
#pragma unroll
    for (int i = 0; i < 4; ++i)
#pragma unroll
      for (int j = 0; j < 4; ++j) acc[i][j] = mfma_bf16(a[i], bm[j], acc[i][j]);
  };

  bf16x8 a0[4], a1[4], b0[4], b1[4];
  loada(a0, 0);
  loadb(b0, 0);
#pragma unroll 1
  for (int s = 0; s < 36; s += 2) {
    loada(a1, s + 1);
    loadb(b1, s + 1);
    step(a0, b0);
    if (s + 2 < 36) {
      loada(a0, s + 2);
      loadb(b0, s + 2);
    }
    step(a1, b1);
  }

  __syncthreads();

  if (MODE == 1) {
    u16* T = Xs;
#pragma unroll
    for (int i = 0; i < 4; ++i)
#pragma unroll
      for (int j = 0; j < 4; ++j) {
        int n = wn * 64 + j * 16 + lm;
        float bs = bias[n];
#pragma unroll
        for (int r = 0; r < 4; ++r) {
          int m = wm * 64 + i * 16 + lq * 4 + r;
          T[m * 136 + n] = f2bf(gelu_exact(acc[i][j][r] + bs));
        }
      }
    __syncthreads();
    int rr = tid >> 1, hf = tid & 1;
    const uint4* src = reinterpret_cast<const uint4*>(T + rr * 136 + hf * 64);
    uint4* dst = reinterpret_cast<uint4*>(OutB + ((size_t)(mt * 128 + rr) * 128 + hf * 64));
#pragma unroll
    for (int k = 0; k < 8; ++k) dst[k] = src[k];
  } else {
    // inline residual: R = V @ M for this tile (f32, K=128)
    f32x4 accR[4][4];
#pragma unroll
    for (int i = 0; i < 4; ++i)
#pragma unroll
      for (int j = 0; j < 4; ++j) accR[i][j] = f32x4{0.f, 0.f, 0.f, 0.f};
#pragma unroll
    for (int cc = 0; cc < 4; ++cc) {
      int k0 = cc * 32 + lq * 8;
      bf16x8 af[4], bfr[4];
#pragma unroll
      for (int i = 0; i < 4; ++i)
        af[i] = *reinterpret_cast<const bf16x8*>(
            Vin + (size_t)(mt * 128 + wm * 64 + i * 16 + lm) * 128 + k0);
#pragma unroll
      for (int j = 0; j < 4; ++j)
        bfr[j] = *reinterpret_cast<const bf16x8*>(
            Mpk + (size_t)b * 16384 + (size_t)((cc * 8 + wn * 4 + j) * 64 + lane) * 8);
#pragma unroll
      for (int i = 0; i < 4; ++i)
#pragma unroll
        for (int j = 0; j < 4; ++j) accR[i][j] = mfma_bf16(af[i], bfr[j], accR[i][j]);
    }

    float* T = reinterpret_cast<float*>(Xs);  // [128][132] f32 = 67584 B
#pragma unroll
    for (int i = 0; i < 4; ++i)
#pragma unroll
      for (int j = 0; j < 4; ++j) {
        int n = wn * 64 + j * 16 + lm;
        float bs = bias[n];
#pragma unroll
        for (int r = 0; r < 4; ++r) {
          int m = wm * 64 + i * 16 + lq * 4 + r;
          T[n * 132 + m] = acc[i][j][r] + bs + accR[i][j][r];
        }
      }
    __syncthreads();
    int rr = tid >> 1, hf = tid & 1;
    const uint4* src = reinterpret_cast<const uint4*>(T + rr * 132 + hf * 64);
    uint4* dst = reinterpret_cast<uint4*>(
        OutF + ((size_t)(b * 128 + rr) * 4096 + (mt & 31) * 128 + hf * 64));
#pragma unroll
    for (int k = 0; k < 16; ++k) dst[k] = src[k];
  }
}

// ---------------- S = K^T Q, split-K=8 -> f32 partials ----------------
__global__ __launch_bounds__(256, 2) void attn_s(const u16* __restrict__ QP,
                                                 const u16* __restrict__ KP,
                                                 float* __restrict__ SP) {
  const int tid = threadIdx.x;
  const int lane = tid & 63;
  const int wv = tid >> 6, wm = wv >> 1, wn = wv & 1;
  const int lm = lane & 15, lq = lane >> 4;
  int mt = blockIdx.x;
  mt = (mt & 7) * 16 + (mt >> 3);  // 128 blocks, bijective
  const int b = mt >> 3, sp = mt & 7;

  f32x4 acc[4][4];
#pragma unroll
  for (int i = 0; i < 4; ++i)
#pragma unroll
    for (int j = 0; j < 4; ++j) acc[i][j] = f32x4{0.f, 0.f, 0.f, 0.f};

#pragma unroll
  for (int ksl = 0; ksl < 16; ++ksl) {
    const int ks = sp * 16 + ksl;
    bf16x8 af[4], bfr[4];
#pragma unroll
    for (int i = 0; i < 4; ++i)
      af[i] = *reinterpret_cast<const bf16x8*>(
          KP + (size_t)(((b * 128 + ks) * 8 + wm * 4 + i) * 64 + lane) * 8);
#pragma unroll
    for (int j = 0; j < 4; ++j)
      bfr[j] = *reinterpret_cast<const bf16x8*>(
          QP + (size_t)(((b * 128 + ks) * 8 + wn * 4 + j) * 64 + lane) * 8);
#pragma unroll
    for (int i = 0; i < 4; ++i)
#pragma unroll
      for (int j = 0; j < 4; ++j) acc[i][j] = mfma_bf16(af[i], bfr[j], acc[i][j]);
  }

  float* out = SP + (size_t)(b * 8 + sp) * 16384;
#pragma unroll
  for (int i = 0; i < 4; ++i)
#pragma unroll
    for (int j = 0; j < 4; ++j)
#pragma unroll
      for (int r = 0; r < 4; ++r)
        out[(wm * 64 + i * 16 + lq * 4 + r) * 128 + wn * 64 + j * 16 + lm] =
            acc[i][j][r];
}

// ---- fused: reduce partials + softmax + M=Pspe@A + pack M both ways -------
__global__ __launch_bounds__(256, 1) void attn_rm(const float* __restrict__ SP,
                                                  const float* __restrict__ Pspe,
                                                  u16* __restrict__ Mpack,
                                                  u16* __restrict__ Mpack2) {
  __shared__ float Sf[128 * 129];  // 66048 B
  __shared__ u16 AT[128 * 136];    // 34816 B
  const int b = blockIdx.x;
  const int tid = threadIdx.x;
  const int lane = tid & 63;
  const int wv = tid >> 6, wm = wv >> 1, wn = wv & 1;
  const int lm = lane & 15, lq = lane >> 4;

#pragma unroll
  for (int it = 0; it < 64; ++it) {
    int id = it * 256 + tid;
    int rl = id >> 7, d = id & 127;
    const float* p = SP + (size_t)b * 8 * 16384 + (size_t)rl * 128 + d;
    float s = 0.f;
#pragma unroll
    for (int sp = 0; sp < 8; ++sp) s += p[(size_t)sp * 16384];
    Sf[rl * 129 + d] = s * 0.015625f;  // /sqrt(4096)
  }
  __syncthreads();

  {
    int c = tid >> 1, hf = tid & 1;
    float* row = Sf + c * 129 + hf * 64;
    float mx = -3.4e38f;
#pragma unroll
    for (int k = 0; k < 64; ++k) mx = fmaxf(mx, row[k]);
    mx = fmaxf(mx, __shfl_xor(mx, 1));
    float s = 0.f;
#pragma unroll
    for (int k = 0; k < 64; ++k) {
      float e = __expf(row[k] - mx);
      row[k] = e;
      s += e;
    }
    s += __shfl_xor(s, 1);
    float inv = 1.0f / s;
#pragma unroll
    for (int k = 0; k < 64; ++k) AT[(hf * 64 + k) * 136 + c] = f2bf(row[k] * inv);
  }
  __syncthreads();

  // M = Pspe @ A
  f32x4 acc2[4][4];
#pragma unroll
  for (int i = 0; i < 4; ++i)
#pragma unroll
    for (int j = 0; j < 4; ++j) acc2[i][j] = f32x4{0.f, 0.f, 0.f, 0.f};
  const float* P = Pspe + (size_t)b * 128 * 128;
#pragma unroll
  for (int cc = 0; cc < 4; ++cc) {
    int e0 = cc * 32 + lq * 8;
    bf16x8 af[4], bfr[4];
#pragma unroll
    for (int i = 0; i < 4; ++i) {
      const float* p = P + (size_t)(wm * 64 + i * 16 + lm) * 128 + e0;
      union { u16 u[8]; bf16x8 v; } cvt;
#pragma unroll
      for (int e = 0; e < 8; ++e) cvt.u[e] = f2bf(p[e]);
      af[i] = cvt.v;
    }
#pragma unroll
    for (int j = 0; j < 4; ++j)
      bfr[j] = *reinterpret_cast<const bf16x8*>(AT + (wn * 64 + j * 16 + lm) * 136 + e0);
#pragma unroll
    for (int i = 0; i < 4; ++i)
#pragma unroll
      for (int j = 0; j < 4; ++j) acc2[i][j] = mfma_bf16(af[i], bfr[j], acc2[i][j]);
  }

  // M^T [d][c] into Ml (aliases Sf)
  u16* Ml = reinterpret_cast<u16*>(Sf);  // [128][136]
#pragma unroll
  for (int i = 0; i < 4; ++i)
#pragma unroll
    for (int j = 0; j < 4; ++j)
#pragma unroll
      for (int r = 0; r < 4; ++r)
        Ml[(wn * 64 + j * 16 + lm) * 136 + (wm * 64 + i * 16 + lq * 4 + r)] =
            f2bf(acc2[i][j][r]);
  __syncthreads();

  // Mpack: fragments with (frag-row = d, k = c)  [for f2' V@M residual]
#pragma unroll
  for (int it = 0; it < 8; ++it) {
    int item = tid + it * 256;
    int l2 = item & 63, nb = (item >> 6) & 7, cc2 = item >> 9;
    int d = nb * 16 + (l2 & 15), c0 = cc2 * 32 + (l2 >> 4) * 8;
    *reinterpret_cast<uint4*>(Mpack + (size_t)b * 16384 + (size_t)item * 8) =
        *reinterpret_cast<const uint4*>(Ml + d * 136 + c0);
  }
  // Mpack2: fragments with (frag-row = c, k = d)  [for wfold1]
#pragma unroll
  for (int it = 0; it < 8; ++it) {
    int item = tid + it * 256;
    int l2 = item & 63, nb = (item >> 6) & 7, cc2 = item >> 9;
    int c = nb * 16 + (l2 & 15), d0 = cc2 * 32 + (l2 >> 4) * 8;
    u16 tmp[8];
#pragma unroll
    for (int e = 0; e < 8; ++e) tmp[e] = Ml[(d0 + e) * 136 + c];
    *reinterpret_cast<uint4*>(Mpack2 + (size_t)b * 16384 + (size_t)item * 8) =
        *reinterpret_cast<const uint4*>(tmp);
  }
}

// ---- wfold1: W1'[co][c,tap] = sum_d W1[co][d,tap] * M[c][d] ---------------
// grid 144 = b*9 + tap; output in conv B-frag layout per batch.
__global__ __launch_bounds__(256, 2) void wfold1(const u16* __restrict__ W1pk,
                                                 const u16* __restrict__ Mpk2,
                                                 u16* __restrict__ Wf1) {
  __shared__ u16 T[128 * 136];
  const int tid = threadIdx.x;
  const int lane = tid & 63, wv = tid >> 6;
  const int wm = wv >> 1, wn = wv & 1;
  const int lm = lane & 15, lq = lane >> 4;
  const int b = blockIdx.x / 9, tap = blockIdx.x % 9;

  f32x4 acc[4][4];
#pragma unroll
  for (int i = 0; i < 4; ++i)
#pragma unroll
    for (int j = 0; j < 4; ++j) acc[i][j] = f32x4{0.f, 0.f, 0.f, 0.f};

#pragma unroll
  for (int cc = 0; cc < 4; ++cc) {
    bf16x8 af[4], bfr[4];
    // A: W1 tap fragments (frag-row = co, k = d) — Wpk B-frags reinterpreted
#pragma unroll
    for (int i = 0; i < 4; ++i)
      af[i] = *reinterpret_cast<const bf16x8*>(
          W1pk + (size_t)(((tap * 4 + cc) * 8 + wm * 4 + i) * 64 + lane) * 8);
    // B: M fragments (frag-row = c, k = d)
#pragma unroll
    for (int j = 0; j < 4; ++j)
      bfr[j] = *reinterpret_cast<const bf16x8*>(
          Mpk2 + (size_t)b * 16384 + (size_t)((cc * 8 + wn * 4 + j) * 64 + lane) * 8);
#pragma unroll
    for (int i = 0; i < 4; ++i)
#pragma unroll
      for (int j = 0; j < 4; ++j) acc[i][j] = mfma_bf16(af[i], bfr[j], acc[i][j]);
  }

  // T[co][c] natural
#pragma unroll
  for (int i = 0; i < 4; ++i)
#pragma unroll
    for (int j = 0; j < 4; ++j)
#pragma unroll
      for (int r = 0; r < 4; ++r)
        T[(wm * 64 + i * 16 + lq * 4 + r) * 136 + wn * 64 + j * 16 + lm] =
            f2bf(acc[i][j][r]);
  __syncthreads();

  // pack into conv B-frag layout: [step=tap*4+cc2][cb=co>>4][lane][8], k=c
#pragma unroll
  for (int it = 0; it < 8; ++it) {
    int item = tid + it * 256;  // 0..2047
    int L = item & 63, nb = (item >> 6) & 7, cc2 = item >> 9;
    int co = nb * 16 + (L & 15);
    int c0 = cc2 * 32 + (L >> 4) * 8;
    *reinterpret_cast<uint4*>(
        Wf1 + (size_t)b * 147456 +
        ((size_t)(((tap * 4 + cc2) * 8 + nb) * 64 + L)) * 8) =
        *reinterpret_cast<const uint4*>(T + co * 136 + c0);
  }
}

extern "C" void kernel_launch(void* const* d_in, const int* in_sizes, int n_in,
                              void* d_out, int out_size, void* d_ws, size_t ws_size,
                              hipStream_t stream) {
  const float* F_in = (const float*)d_in[0];
  const float* Pspe = (const float*)d_in[1];
  const float* q_w = (const float*)d_in[2];
  const float* q_b = (const float*)d_in[3];
  const float* k_w = (const float*)d_in[4];
  const float* k_b = (const float*)d_in[5];
  const float* v_w = (const float*)d_in[6];
  const float* v_b = (const float*)d_in[7];
  const float* f1_w = (const float*)d_in[8];
  const float* f1_b = (const float*)d_in[9];
  const float* f2_w = (const float*)d_in[10];
  const float* f2_b = (const float*)d_in[11];
  float* out = (float*)d_out;

  char* ws = (char*)d_ws;
  const size_t SZ = 16777216;  // 65536*128*2 bytes
  u16* X = (u16*)(ws);                   // NHWC bf16 input; SP aliases later
  u16* QP = (u16*)(ws + SZ);             // packed Q; later Hid
  u16* KP = (u16*)(ws + 2 * SZ);         // packed K
  u16* V = (u16*)(ws + 3 * SZ);          // natural V (alive until f2')
  u16* Wpk = (u16*)(ws + 4 * SZ);                    // 1,474,560 B
  u16* Mpk = (u16*)(ws + 4 * SZ + 1474560);          // 524,288 B
  u16* Mpk2 = (u16*)(ws + 4 * SZ + 1998848);         // 524,288 B
  u16* Wf1 = (u16*)(ws + 4 * SZ + 2523136);          // 4,718,592 B -> ~74.4 MB
  float* SP = (float*)ws;                // 8.39 MB partials — aliases X (dead)
  u16* Hid = QP;                         // f1' output — aliases QP (dead)

  pack_xw<<<1384, 256, 0, stream>>>(F_in, X, q_w, k_w, v_w, f1_w, f2_w, Wpk);
  conv_qkv<<<1024, 256, 0, stream>>>(X, Wpk, q_b, k_b, v_b, QP, KP, V);
  attn_s<<<128, 256, 0, stream>>>(QP, KP, SP);
  attn_rm<<<16, 256, 0, stream>>>(SP, Pspe, Mpk, Mpk2);
  wfold1<<<144, 256, 0, stream>>>(Wpk + 3 * 147456, Mpk2, Wf1);
  conv_gemm<1><<<512, 256, 0, stream>>>(V, Wf1, f1_b, Hid, nullptr, nullptr,
                                        nullptr);
  conv_gemm<3><<<512, 256, 0, stream>>>(Hid, Wpk + 4 * 147456, f2_b, nullptr,
                                        out, V, Mpk);
}

// Round 12
// 172.651 us; speedup vs baseline: 1.2576x; 1.0284x over previous
//
#include <hip/hip_runtime.h>
#include <cmath>

typedef unsigned short u16;
typedef __bf16 bf16x8 __attribute__((ext_vector_type(8)));
typedef float f32x4 __attribute__((ext_vector_type(4)));

__device__ __forceinline__ u16 f2bf(float f) {
  unsigned u = __float_as_uint(f);
  u += 0x7fffu + ((u >> 16) & 1u);
  return (u16)(u >> 16);
}
__device__ __forceinline__ float bf2f(u16 h) {
  return __uint_as_float(((unsigned)h) << 16);
}
__device__ __forceinline__ f32x4 mfma_bf16(bf16x8 a, bf16x8 b, f32x4 c) {
  return __builtin_amdgcn_mfma_f32_16x16x32_bf16(a, b, c, 0, 0, 0);
}
__device__ __forceinline__ float gelu_exact(float x) {
  return 0.5f * x * (1.0f + erff(x * 0.70710678118654752440f));
}

// B=16, C=128, H=64, W=64, HW=4096, NPOS=65536
// LDS A-tile: [4*66 rows][136 u16] — 272B row stride (128ch + 8 pad).
// 272B = 68 banks = 4 mod 32 -> b128 reads spread uniformly, no XOR needed.
#define ROWB 272

// ---------------- merged pack: X (NCHW f32 -> NHWC bf16) + weights ----------
__global__ __launch_bounds__(256) void pack_xw(
    const float* __restrict__ Fin, u16* __restrict__ X,
    const float* __restrict__ w0, const float* __restrict__ w1,
    const float* __restrict__ w2, const float* __restrict__ w3,
    const float* __restrict__ w4, u16* __restrict__ Wpk) {
  __shared__ float T[64 * 129];
  const int tid = threadIdx.x;
  if (blockIdx.x < 1024) {
    const int b = blockIdx.x >> 6, y = blockIdx.x & 63;
#pragma unroll
    for (int i = 0; i < 32; ++i) {
      int idx = tid + i * 256;
      int c = idx >> 6, x = idx & 63;
      T[x * 129 + c] = Fin[(size_t)(b * 128 + c) * 4096 + y * 64 + x];
    }
    __syncthreads();
#pragma unroll
    for (int i = 0; i < 4; ++i) {
      int chunk = tid + i * 256;
      int x = chunk >> 4;
      int c0 = (chunk & 15) * 8;
      u16 tmp[8];
#pragma unroll
      for (int e = 0; e < 8; ++e) tmp[e] = f2bf(T[x * 129 + c0 + e]);
      *reinterpret_cast<uint4*>(X + ((size_t)((b * 64 + y) * 64 + x) * 128 + c0)) =
          *reinterpret_cast<const uint4*>(tmp);
    }
  } else {
    int gid = (blockIdx.x - 1024) * 256 + tid;  // 92160 total
    int lane = gid & 63;
    int nblk = (gid >> 6) & 7;
    int step = (gid >> 9) % 36;
    int conv = gid / (512 * 36);
    if (conv >= 5) return;
    const float* w = conv == 0 ? w0 : conv == 1 ? w1 : conv == 2 ? w2 : conv == 3 ? w3 : w4;
    int tap = step >> 2, cc = step & 3;
    int dy = tap / 3, dx = tap % 3;
    int co = nblk * 16 + (lane & 15);
    int ci0 = cc * 32 + (lane >> 4) * 8;
    u16 tmp[8];
#pragma unroll
    for (int e = 0; e < 8; ++e)
      tmp[e] = f2bf(w[((size_t)(co * 128 + ci0 + e) * 3 + dy) * 3 + dx]);
    size_t off = ((size_t)conv * 36 * 8 * 64 + (size_t)((step * 8 + nblk) * 64 + lane)) * 8;
    *reinterpret_cast<uint4*>(Wpk + off) = *reinterpret_cast<const uint4*>(tmp);
  }
}

// ======== staging: rows y0-1..y0+2, x-halo, linear 272B-stride layout ======
__device__ __forceinline__ void stage_tile(const u16* __restrict__ Xin, char* Xsb,
                                           int tid, int b, int y0) {
#pragma unroll
  for (int i = 0; i < 16; ++i) {
    int j = tid + i * 256;
    int row = j >> 4;
    int c16 = j & 15;
    int ys = row >> 6, x = row & 63;
    int ysrc = y0 - 1 + ys;
    uint4 val = make_uint4(0u, 0u, 0u, 0u);
    if ((unsigned)ysrc < 64u)
      val = *reinterpret_cast<const uint4*>(
          Xin + ((size_t)((b * 64 + ysrc) * 64 + x) * 128 + c16 * 8));
    *reinterpret_cast<uint4*>(Xsb + (ys * 66 + x + 1) * ROWB + c16 * 16) = val;
  }
  if (tid < 128) {
    int ys = tid >> 5, side = (tid >> 4) & 1, c16 = tid & 15;
    int xs = side ? 65 : 0;
    *reinterpret_cast<uint4*>(Xsb + (ys * 66 + xs) * ROWB + c16 * 16) =
        make_uint4(0u, 0u, 0u, 0u);
  }
}

// ---------------- fused QKV conv3x3, N-split tile M128xN64, pipelined -------
__global__ __launch_bounds__(256, 2) void conv_qkv(
    const u16* __restrict__ Xin, const u16* __restrict__ Wp,
    const float* __restrict__ qb, const float* __restrict__ kb,
    const float* __restrict__ vb, u16* __restrict__ QP,
    u16* __restrict__ KP, u16* __restrict__ Vout) {
  __shared__ alignas(16) char Xsb[4 * 66 * ROWB];  // 71808 B
  const int tid = threadIdx.x;
  const int lane = tid & 63;
  const int wv = tid >> 6;
  const int wm = wv >> 1, wn = wv & 1;
  int mt = blockIdx.x;
  mt = (mt & 7) * 128 + (mt >> 3);  // 1024 blocks, bijective XCD swizzle
  const int b = mt >> 6;
  const int r = mt & 63;
  const int yp = r >> 1;      // y-pair 0..31
  const int nh = r & 1;       // N half
  const int y0 = yp * 2;

  stage_tile(Xin, Xsb, tid, b, y0);
  __syncthreads();

  f32x4 acc[3][4][2];
#pragma unroll
  for (int c = 0; c < 3; ++c)
#pragma unroll
    for (int i = 0; i < 4; ++i)
#pragma unroll
      for (int j = 0; j < 2; ++j) acc[c][i][j] = f32x4{0.f, 0.f, 0.f, 0.f};

  const int lm = lane & 15, lq = lane >> 4;
  const int abase = lm * ROWB + lq * 16;
  const u16* wb = Wp + (size_t)(((nh * 4 + wn * 2) * 64) + lane) * 8;

  auto loada = [&](bf16x8 (&d)[4], int s) {
    int tap = s >> 2, cc = s & 3;
    int dy = (tap * 11) >> 5;
    int dx = tap - dy * 3;
    int roff = ((wm + dy) * 66 + dx) * ROWB + cc * 64 + abase;
#pragma unroll
    for (int i = 0; i < 4; ++i)
      d[i] = *reinterpret_cast<const bf16x8*>(Xsb + roff + i * (16 * ROWB));
  };
  auto loadb = [&](bf16x8 (&d)[6], int s) {
#pragma unroll
    for (int cv = 0; cv < 3; ++cv)
#pragma unroll
      for (int j = 0; j < 2; ++j)
        d[cv * 2 + j] = *reinterpret_cast<const bf16x8*>(
            wb + (size_t)cv * 147456 + (size_t)s * 4096 + j * 512);
  };
  auto step = [&](bf16x8 (&a)[4], bf16x8 (&bm)[6]) {
#pragma unroll
    for (int cv = 0; cv < 3; ++cv)
#pragma unroll
      for (int i = 0; i < 4; ++i)
#pragma unroll
        for (int j = 0; j < 2; ++j)
          acc[cv][i][j] = mfma_bf16(a[i], bm[cv * 2 + j], acc[cv][i][j]);
  };

  bf16x8 a0[4], a1[4], b0[6], b1[6];
  loada(a0, 0);
  loadb(b0, 0);
#pragma unroll 1
  for (int s = 0; s < 36; s += 2) {
    loada(a1, s + 1);
    loadb(b1, s + 1);
    step(a0, b0);
    if (s + 2 < 36) {
      loada(a0, s + 2);
      loadb(b0, s + 2);
    }
    step(a1, b1);
  }

  __syncthreads();  // Xs dead; reuse for epilogues

  // ---- Q, K: fragment-packed epilogue ----
  u16* T = reinterpret_cast<u16*>(Xsb);  // [64][136]
#pragma unroll
  for (int cv = 0; cv < 2; ++cv) {
    const float* bias = cv == 0 ? qb : kb;
    u16* OutB = cv == 0 ? QP : KP;
#pragma unroll
    for (int i = 0; i < 4; ++i)
#pragma unroll
      for (int j = 0; j < 2; ++j) {
        int nloc = wn * 32 + j * 16 + lm;
        float bs = bias[nh * 64 + nloc];
#pragma unroll
        for (int rr = 0; rr < 4; ++rr) {
          int m = wm * 64 + i * 16 + lq * 4 + rr;
          T[nloc * 136 + m] = f2bf(acc[cv][i][j][rr] + bs);
        }
      }
    __syncthreads();
#pragma unroll
    for (int it = 0; it < 4; ++it) {
      int item = tid + it * 256;  // 0..1023
      int l = item & 63, cbl = (item >> 6) & 3, ksl = item >> 8;
      int c = cbl * 16 + (l & 15);
      int mloc = ksl * 32 + (l >> 4) * 8;
      int ks = yp * 4 + ksl, cb = nh * 4 + cbl;
      *reinterpret_cast<uint4*>(
          OutB + (size_t)(((b * 128 + ks) * 8 + cb) * 64 + l) * 8) =
          *reinterpret_cast<const uint4*>(T + c * 136 + mloc);
    }
    __syncthreads();
  }

  // ---- V: natural [pos][ch] ----
  u16* Tv = reinterpret_cast<u16*>(Xsb);  // [128][72]
#pragma unroll
  for (int i = 0; i < 4; ++i)
#pragma unroll
    for (int j = 0; j < 2; ++j) {
      int nloc = wn * 32 + j * 16 + lm;
      float bs = vb[nh * 64 + nloc];
#pragma unroll
      for (int rr = 0; rr < 4; ++rr) {
        int m = wm * 64 + i * 16 + lq * 4 + rr;
        Tv[m * 72 + nloc] = f2bf(acc[2][i][j][rr] + bs);
      }
    }
  __syncthreads();
  {
    int rr = tid >> 1, q = tid & 1;
    const uint4* src = reinterpret_cast<const uint4*>(Tv + rr * 72 + q * 32);
    uint4* dst = reinterpret_cast<uint4*>(
        Vout + ((size_t)((b * 32 + yp) * 128 + rr) * 128 + nh * 64 + q * 32));
#pragma unroll
    for (int k = 0; k < 4; ++k) dst[k] = src[k];
  }
}

// ---------------- FFN convs, pipelined ----------------
// MODE 1: f1' (per-batch folded weights, gelu -> natural bf16 Hid)
// MODE 3: f2' (f32 NCHW out + inline V@M residual)
template <int MODE>
__global__ __launch_bounds__(256, 2) void conv_gemm(
    const u16* __restrict__ Xin, const u16* __restrict__ Wp,
    const float* __restrict__ bias, u16* __restrict__ OutB,
    float* __restrict__ OutF, const u16* __restrict__ Vin,
    const u16* __restrict__ Mpk) {
  __shared__ alignas(16) char Xsb[4 * 66 * ROWB];  // 71808 B
  const int tid = threadIdx.x;
  const int lane = tid & 63;
  const int wv = tid >> 6;
  const int wm = wv >> 1, wn = wv & 1;
  int mt = blockIdx.x;
  mt = (mt & 7) * 64 + (mt >> 3);
  const int b = mt >> 5;
  const int y0 = (mt & 31) * 2;

  stage_tile(Xin, Xsb, tid, b, y0);
  __syncthreads();

  f32x4 acc[4][4];
#pragma unroll
  for (int i = 0; i < 4; ++i)
#pragma unroll
    for (int j = 0; j < 4; ++j) acc[i][j] = f32x4{0.f, 0.f, 0.f, 0.f};

  const int lm = lane & 15, lq = lane >> 4;
  const int abase = lm * ROWB + lq * 16;
  const u16* wb = Wp + (MODE == 1 ? (size_t)b * 147456 : (size_t)0) +
                  (size_t)((wn * 4 * 64) + lane) * 8;

  auto loada = [&](bf16x8 (&d)[4], int s) {
    int tap = s >> 2, cc = s & 3;
    int dy = (tap * 11) >> 5;
    int dx = tap - dy * 3;
    int roff = ((wm + dy) * 66 + dx) * ROWB + cc * 64 + abase;
#pragma unroll
    for (int i = 0; i < 4; ++i)
      d[i] = *reinterpret_cast<const bf16x8*>(Xsb + roff + i * (16 * ROWB));
  };
  auto loadb = [&](bf16x8 (&d)[4], int s) {
#pragma unroll
    for (int j = 0; j < 4; ++j)
      d[j] = *reinterpret_cast<const bf16x8*>(wb + (size_t)s * 4096 + j * 512);
  };
  auto step = [&](bf16x8 (&a)[4], bf16x8 (&bm)[4]) {
#pragma unroll
    for (int i = 0; i < 4; ++i)
#pragma unroll
      for (int j = 0; j < 4; ++j) acc[i][j] = mfma_bf16(a[i], bm[j], acc[i][j]);
  };

  bf16x8 a0[4], a1[4], b0[4], b1[4];
  loada(a0, 0);
  loadb(b0, 0);
#pragma unroll 1
  for (int s = 0; s < 36; s += 2) {
    loada(a1, s + 1);
    loadb(b1, s + 1);
    step(a0, b0);
    if (s + 2 < 36) {
      loada(a0, s + 2);
      loadb(b0, s + 2);
    }
    step(a1, b1);
  }

  __syncthreads();

  if (MODE == 1) {
    u16* T = reinterpret_cast<u16*>(Xsb);
#pragma unroll
    for (int i = 0; i < 4; ++i)
#pragma unroll
      for (int j = 0; j < 4; ++j) {
        int n = wn * 64 + j * 16 + lm;
        float bs = bias[n];
#pragma unroll
        for (int r = 0; r < 4; ++r) {
          int m = wm * 64 + i * 16 + lq * 4 + r;
          T[m * 136 + n] = f2bf(gelu_exact(acc[i][j][r] + bs));
        }
      }
    __syncthreads();
    int rr = tid >> 1, hf = tid & 1;
    const uint4* src = reinterpret_cast<const uint4*>(T + rr * 136 + hf * 64);
    uint4* dst = reinterpret_cast<uint4*>(OutB + ((size_t)(mt * 128 + rr) * 128 + hf * 64));
#pragma unroll
    for (int k = 0; k < 8; ++k) dst[k] = src[k];
  } else {
    // inline residual: R = V @ M for this tile (f32, K=128)
    f32x4 accR[4][4];
#pragma unroll
    for (int i = 0; i < 4; ++i)
#pragma unroll
      for (int j = 0; j < 4; ++j) accR[i][j] = f32x4{0.f, 0.f, 0.f, 0.f};
#pragma unroll
    for (int cc = 0; cc < 4; ++cc) {
      int k0 = cc * 32 + lq * 8;
      bf16x8 af[4], bfr[4];
#pragma unroll
      for (int i = 0; i < 4; ++i)
        af[i] = *reinterpret_cast<const bf16x8*>(
            Vin + (size_t)(mt * 128 + wm * 64 + i * 16 + lm) * 128 + k0);
#pragma unroll
      for (int j = 0; j < 4; ++j)
        bfr[j] = *reinterpret_cast<const bf16x8*>(
            Mpk + (size_t)b * 16384 + (size_t)((cc * 8 + wn * 4 + j) * 64 + lane) * 8);
#pragma unroll
      for (int i = 0; i < 4; ++i)
#pragma unroll
        for (int j = 0; j < 4; ++j) accR[i][j] = mfma_bf16(af[i], bfr[j], accR[i][j]);
    }

    float* T = reinterpret_cast<float*>(Xsb);  // [128][132] f32 = 67584 B
#pragma unroll
    for (int i = 0; i < 4; ++i)
#pragma unroll
      for (int j = 0; j < 4; ++j) {
        int n = wn * 64 + j * 16 + lm;
        float bs = bias[n];
#pragma unroll
        for (int r = 0; r < 4; ++r) {
          int m = wm * 64 + i * 16 + lq * 4 + r;
          T[n * 132 + m] = acc[i][j][r] + bs + accR[i][j][r];
        }
      }
    __syncthreads();
    int rr = tid >> 1, hf = tid & 1;
    const uint4* src = reinterpret_cast<const uint4*>(T + rr * 132 + hf * 64);
    uint4* dst = reinterpret_cast<uint4*>(
        OutF + ((size_t)(b * 128 + rr) * 4096 + (mt & 31) * 128 + hf * 64));
#pragma unroll
    for (int k = 0; k < 16; ++k) dst[k] = src[k];
  }
}

// ---------------- S = K^T Q, split-K=8 -> f32 partials ----------------
__global__ __launch_bounds__(256, 2) void attn_s(const u16* __restrict__ QP,
                                                 const u16* __restrict__ KP,
                                                 float* __restrict__ SP) {
  const int tid = threadIdx.x;
  const int lane = tid & 63;
  const int wv = tid >> 6, wm = wv >> 1, wn = wv & 1;
  const int lm = lane & 15, lq = lane >> 4;
  int mt = blockIdx.x;
  mt = (mt & 7) * 16 + (mt >> 3);  // 128 blocks, bijective
  const int b = mt >> 3, sp = mt & 7;

  f32x4 acc[4][4];
#pragma unroll
  for (int i = 0; i < 4; ++i)
#pragma unroll
    for (int j = 0; j < 4; ++j) acc[i][j] = f32x4{0.f, 0.f, 0.f, 0.f};

#pragma unroll
  for (int ksl = 0; ksl < 16; ++ksl) {
    const int ks = sp * 16 + ksl;
    bf16x8 af[4], bfr[4];
#pragma unroll
    for (int i = 0; i < 4; ++i)
      af[i] = *reinterpret_cast<const bf16x8*>(
          KP + (size_t)(((b * 128 + ks) * 8 + wm * 4 + i) * 64 + lane) * 8);
#pragma unroll
    for (int j = 0; j < 4; ++j)
      bfr[j] = *reinterpret_cast<const bf16x8*>(
          QP + (size_t)(((b * 128 + ks) * 8 + wn * 4 + j) * 64 + lane) * 8);
#pragma unroll
    for (int i = 0; i < 4; ++i)
#pragma unroll
      for (int j = 0; j < 4; ++j) acc[i][j] = mfma_bf16(af[i], bfr[j], acc[i][j]);
  }

  float* out = SP + (size_t)(b * 8 + sp) * 16384;
#pragma unroll
  for (int i = 0; i < 4; ++i)
#pragma unroll
    for (int j = 0; j < 4; ++j)
#pragma unroll
      for (int r = 0; r < 4; ++r)
        out[(wm * 64 + i * 16 + lq * 4 + r) * 128 + wn * 64 + j * 16 + lm] =
            acc[i][j][r];
}

// ---- fused: reduce partials + softmax + M=Pspe@A + pack M both ways -------
__global__ __launch_bounds__(256, 1) void attn_rm(const float* __restrict__ SP,
                                                  const float* __restrict__ Pspe,
                                                  u16* __restrict__ Mpack,
                                                  u16* __restrict__ Mpack2) {
  __shared__ float Sf[128 * 129];  // 66048 B
  __shared__ u16 AT[128 * 136];    // 34816 B
  const int b = blockIdx.x;
  const int tid = threadIdx.x;
  const int lane = tid & 63;
  const int wv = tid >> 6, wm = wv >> 1, wn = wv & 1;
  const int lm = lane & 15, lq = lane >> 4;

#pragma unroll
  for (int it = 0; it < 64; ++it) {
    int id = it * 256 + tid;
    int rl = id >> 7, d = id & 127;
    const float* p = SP + (size_t)b * 8 * 16384 + (size_t)rl * 128 + d;
    float s = 0.f;
#pragma unroll
    for (int sp = 0; sp < 8; ++sp) s += p[(size_t)sp * 16384];
    Sf[rl * 129 + d] = s * 0.015625f;  // /sqrt(4096)
  }
  __syncthreads();

  {
    int c = tid >> 1, hf = tid & 1;
    float* row = Sf + c * 129 + hf * 64;
    float mx = -3.4e38f;
#pragma unroll
    for (int k = 0; k < 64; ++k) mx = fmaxf(mx, row[k]);
    mx = fmaxf(mx, __shfl_xor(mx, 1));
    float s = 0.f;
#pragma unroll
    for (int k = 0; k < 64; ++k) {
      float e = __expf(row[k] - mx);
      row[k] = e;
      s += e;
    }
    s += __shfl_xor(s, 1);
    float inv = 1.0f / s;
#pragma unroll
    for (int k = 0; k < 64; ++k) AT[(hf * 64 + k) * 136 + c] = f2bf(row[k] * inv);
  }
  __syncthreads();

  // M = Pspe @ A
  f32x4 acc2[4][4];
#pragma unroll
  for (int i = 0; i < 4; ++i)
#pragma unroll
    for (int j = 0; j < 4; ++j) acc2[i][j] = f32x4{0.f, 0.f, 0.f, 0.f};
  const float* P = Pspe + (size_t)b * 128 * 128;
#pragma unroll
  for (int cc = 0; cc < 4; ++cc) {
    int e0 = cc * 32 + lq * 8;
    bf16x8 af[4], bfr[4];
#pragma unroll
    for (int i = 0; i < 4; ++i) {
      const float* p = P + (size_t)(wm * 64 + i * 16 + lm) * 128 + e0;
      union { u16 u[8]; bf16x8 v; } cvt;
#pragma unroll
      for (int e = 0; e < 8; ++e) cvt.u[e] = f2bf(p[e]);
      af[i] = cvt.v;
    }
#pragma unroll
    for (int j = 0; j < 4; ++j)
      bfr[j] = *reinterpret_cast<const bf16x8*>(AT + (wn * 64 + j * 16 + lm) * 136 + e0);
#pragma unroll
    for (int i = 0; i < 4; ++i)
#pragma unroll
      for (int j = 0; j < 4; ++j) acc2[i][j] = mfma_bf16(af[i], bfr[j], acc2[i][j]);
  }

  // M^T [d][c] into Ml (aliases Sf)
  u16* Ml = reinterpret_cast<u16*>(Sf);  // [128][136]
#pragma unroll
  for (int i = 0; i < 4; ++i)
#pragma unroll
    for (int j = 0; j < 4; ++j)
#pragma unroll
      for (int r = 0; r < 4; ++r)
        Ml[(wn * 64 + j * 16 + lm) * 136 + (wm * 64 + i * 16 + lq * 4 + r)] =
            f2bf(acc2[i][j][r]);
  __syncthreads();

  // Mpack: fragments with (frag-row = d, k = c)  [for f2' V@M residual]
#pragma unroll
  for (int it = 0; it < 8; ++it) {
    int item = tid + it * 256;
    int l2 = item & 63, nb = (item >> 6) & 7, cc2 = item >> 9;
    int d = nb * 16 + (l2 & 15), c0 = cc2 * 32 + (l2 >> 4) * 8;
    *reinterpret_cast<uint4*>(Mpack + (size_t)b * 16384 + (size_t)item * 8) =
        *reinterpret_cast<const uint4*>(Ml + d * 136 + c0);
  }
  // Mpack2: fragments with (frag-row = c, k = d)  [for wfold1]
#pragma unroll
  for (int it = 0; it < 8; ++it) {
    int item = tid + it * 256;
    int l2 = item & 63, nb = (item >> 6) & 7, cc2 = item >> 9;
    int c = nb * 16 + (l2 & 15), d0 = cc2 * 32 + (l2 >> 4) * 8;
    u16 tmp[8];
#pragma unroll
    for (int e = 0; e < 8; ++e) tmp[e] = Ml[(d0 + e) * 136 + c];
    *reinterpret_cast<uint4*>(Mpack2 + (size_t)b * 16384 + (size_t)item * 8) =
        *reinterpret_cast<const uint4*>(tmp);
  }
}

// ---- wfold1: W1'[co][c,tap] = sum_d W1[co][d,tap] * M[c][d] ---------------
__global__ __launch_bounds__(256, 2) void wfold1(const u16* __restrict__ W1pk,
                                                 const u16* __restrict__ Mpk2,
                                                 u16* __restrict__ Wf1) {
  __shared__ u16 T[128 * 136];
  const int tid = threadIdx.x;
  const int lane = tid & 63, wv = tid >> 6;
  const int wm = wv >> 1, wn = wv & 1;
  const int lm = lane & 15, lq = lane >> 4;
  const int b = blockIdx.x / 9, tap = blockIdx.x % 9;

  f32x4 acc[4][4];
#pragma unroll
  for (int i = 0; i < 4; ++i)
#pragma unroll
    for (int j = 0; j < 4; ++j) acc[i][j] = f32x4{0.f, 0.f, 0.f, 0.f};

#pragma unroll
  for (int cc = 0; cc < 4; ++cc) {
    bf16x8 af[4], bfr[4];
#pragma unroll
    for (int i = 0; i < 4; ++i)
      af[i] = *reinterpret_cast<const bf16x8*>(
          W1pk + (size_t)(((tap * 4 + cc) * 8 + wm * 4 + i) * 64 + lane) * 8);
#pragma unroll
    for (int j = 0; j < 4; ++j)
      bfr[j] = *reinterpret_cast<const bf16x8*>(
          Mpk2 + (size_t)b * 16384 + (size_t)((cc * 8 + wn * 4 + j) * 64 + lane) * 8);
#pragma unroll
    for (int i = 0; i < 4; ++i)
#pragma unroll
      for (int j = 0; j < 4; ++j) acc[i][j] = mfma_bf16(af[i], bfr[j], acc[i][j]);
  }

#pragma unroll
  for (int i = 0; i < 4; ++i)
#pragma unroll
    for (int j = 0; j < 4; ++j)
#pragma unroll
      for (int r = 0; r < 4; ++r)
        T[(wm * 64 + i * 16 + lq * 4 + r) * 136 + wn * 64 + j * 16 + lm] =
            f2bf(acc[i][j][r]);
  __syncthreads();

#pragma unroll
  for (int it = 0; it < 8; ++it) {
    int item = tid + it * 256;  // 0..2047
    int L = item & 63, nb = (item >> 6) & 7, cc2 = item >> 9;
    int co = nb * 16 + (L & 15);
    int c0 = cc2 * 32 + (L >> 4) * 8;
    *reinterpret_cast<uint4*>(
        Wf1 + (size_t)b * 147456 +
        ((size_t)(((tap * 4 + cc2) * 8 + nb) * 64 + L)) * 8) =
        *reinterpret_cast<const uint4*>(T + co * 136 + c0);
  }
}

extern "C" void kernel_launch(void* const* d_in, const int* in_sizes, int n_in,
                              void* d_out, int out_size, void* d_ws, size_t ws_size,
                              hipStream_t stream) {
  const float* F_in = (const float*)d_in[0];
  const float* Pspe = (const float*)d_in[1];
  const float* q_w = (const float*)d_in[2];
  const float* q_b = (const float*)d_in[3];
  const float* k_w = (const float*)d_in[4];
  const float* k_b = (const float*)d_in[5];
  const float* v_w = (const float*)d_in[6];
  const float* v_b = (const float*)d_in[7];
  const float* f1_w = (const float*)d_in[8];
  const float* f1_b = (const float*)d_in[9];
  const float* f2_w = (const float*)d_in[10];
  const float* f2_b = (const float*)d_in[11];
  float* out = (float*)d_out;

  char* ws = (char*)d_ws;
  const size_t SZ = 16777216;  // 65536*128*2 bytes
  u16* X = (u16*)(ws);                   // NHWC bf16 input; SP aliases later
  u16* QP = (u16*)(ws + SZ);             // packed Q; later Hid
  u16* KP = (u16*)(ws + 2 * SZ);         // packed K
  u16* V = (u16*)(ws + 3 * SZ);          // natural V (alive until f2')
  u16* Wpk = (u16*)(ws + 4 * SZ);                    // 1,474,560 B
  u16* Mpk = (u16*)(ws + 4 * SZ + 1474560);          // 524,288 B
  u16* Mpk2 = (u16*)(ws + 4 * SZ + 1998848);         // 524,288 B
  u16* Wf1 = (u16*)(ws + 4 * SZ + 2523136);          // 4,718,592 B -> ~74.4 MB
  float* SP = (float*)ws;                // 8.39 MB partials — aliases X (dead)
  u16* Hid = QP;                         // f1' output — aliases QP (dead)

  pack_xw<<<1384, 256, 0, stream>>>(F_in, X, q_w, k_w, v_w, f1_w, f2_w, Wpk);
  conv_qkv<<<1024, 256, 0, stream>>>(X, Wpk, q_b, k_b, v_b, QP, KP, V);
  attn_s<<<128, 256, 0, stream>>>(QP, KP, SP);
  attn_rm<<<16, 256, 0, stream>>>(SP, Pspe, Mpk, Mpk2);
  wfold1<<<144, 256, 0, stream>>>(Wpk + 3 * 147456, Mpk2, Wf1);
  conv_gemm<1><<<512, 256, 0, stream>>>(V, Wf1, f1_b, Hid, nullptr, nullptr,
                                        nullptr);
  conv_gemm<3><<<512, 256, 0, stream>>>(Hid, Wpk + 4 * 147456, f2_b, nullptr,
                                        out, V, Mpk);
}